// Round 12
// baseline (317.290 us; speedup 1.0000x reference)
//
#include <hip/hip_runtime.h>
#include <hip/hip_bf16.h>

typedef unsigned short u16;
typedef __attribute__((ext_vector_type(8))) short short8;
typedef __attribute__((ext_vector_type(4))) float floatx4;
typedef __attribute__((ext_vector_type(2))) float f32x2;

#define N_NODES 50000
#define N_EDGES 400000
#define ET      450000   // edges + self loops
#define F_IN    128
#define C1      256      // H*HID
#define HID     64
#define OUTC    64
#define SLOPE   0.2f

__device__ __forceinline__ float bf2f(u16 v) {
    return __uint_as_float(((unsigned)v) << 16);
}
__device__ __forceinline__ float bflo(unsigned u) { return __uint_as_float(u << 16); }
__device__ __forceinline__ float bfhi(unsigned u) { return __uint_as_float(u & 0xffff0000u); }
__device__ __forceinline__ u16 f2bf(float f) {   // round-to-nearest-even
    unsigned u = __float_as_uint(f);
    return (u16)((u + 0x7fffu + ((u >> 16) & 1u)) >> 16);
}
__device__ __forceinline__ f32x2 up2(unsigned u) {
    f32x2 r; r.x = bflo(u); r.y = bfhi(u); return r;
}
// single-instruction cross-lane add via DPP (no LDS, no lgkm wait)
template<int CTRL>
__device__ __forceinline__ float dpp_add(float x) {
    return x + __int_as_float(__builtin_amdgcn_update_dpp(
        0, __float_as_int(x), CTRL, 0xF, 0xF, true));
}
// reduce over 16-lane group: xor1, xor2, mirror-8, mirror-16
__device__ __forceinline__ float red16(float p) {
    p = dpp_add<0xB1>(p);
    p = dpp_add<0x4E>(p);
    p = dpp_add<0x141>(p);
    p = dpp_add<0x140>(p);
    return p;
}
// inline dtype detection: wave-ballot over first 64 words of x.
__device__ __forceinline__ bool detect_f32(const unsigned* __restrict__ xw) {
    unsigned w = xw[threadIdx.x & 63];
    unsigned aexp = (w >> 7) & 0xFFu;
    unsigned long long b = __ballot(aexp >= 170u || aexp <= 40u);
    return __popcll(b) >= 16;
}

// ---------------- fused param convert + hist zero ---------------------------
__global__ __launch_bounds__(256) void convert_all_kernel(
    const unsigned* __restrict__ xw,
    const void* wl1, const void* wr1, const void* wl2, const void* wr2,
    const void* s0, const void* s1, const void* s2, const void* s3,
    const void* s4, const void* s5, const void* s6, const void* s7,
    u16* __restrict__ wt, u16* __restrict__ prm, int* __restrict__ hist)
{
    if (blockIdx.x >= 385) {
        int idx = (blockIdx.x - 385) * 256 + threadIdx.x;
        if (idx < N_NODES) hist[idx] = 0;
        return;
    }
    bool f32m = detect_f32(xw);
    if (blockIdx.x == 384) {
        for (int t = threadIdx.x; t < 1280; t += 256) {
            const void* src; int local;
            if      (t < 256)  { src = s0; local = t; }
            else if (t < 512)  { src = s1; local = t - 256; }
            else if (t < 768)  { src = s2; local = t - 512; }
            else if (t < 1024) { src = s3; local = t - 768; }
            else if (t < 1088) { src = s4; local = t - 1024; }
            else if (t < 1152) { src = s5; local = t - 1088; }
            else if (t < 1216) { src = s6; local = t - 1152; }
            else               { src = s7; local = t - 1216; }
            prm[t] = f32m ? f2bf(((const float*)src)[local]) : ((const u16*)src)[local];
        }
        return;
    }
    int t = blockIdx.x * 256 + threadIdx.x;   // 98304 total
    const void* src; int local, k, n, K, base;
    if (t < 32768)      { src = wl1; local = t;         k = local >> 8; n = local & 255; K = 128; base = 0; }
    else if (t < 65536) { src = wr1; local = t - 32768; k = local >> 8; n = local & 255; K = 128; base = 32768; }
    else if (t < 81920) { src = wl2; local = t - 65536; k = local >> 6; n = local & 63;  K = 256; base = 65536; }
    else                { src = wr2; local = t - 81920; k = local >> 6; n = local & 63;  K = 256; base = 81920; }
    u16 v = f32m ? f2bf(((const float*)src)[local]) : ((const u16*)src)[local];
    wt[base + n * K + k] = v;
}

// ---------------- CSR build (by dst) ----------------
__global__ __launch_bounds__(256) void hist_kernel(const int* __restrict__ ei,
                                                   int* __restrict__ hist)
{
    int t = blockIdx.x * 256 + threadIdx.x;
    if (t >= ET) return;
    int d = (t < N_EDGES) ? ei[N_EDGES + t] : t - N_EDGES;
    atomicAdd(&hist[d], 1);
}

__global__ __launch_bounds__(256) void scan1_kernel(const int* __restrict__ hist,
                                                    int* __restrict__ rowptr,
                                                    int* __restrict__ bsum)
{
    int t = threadIdx.x;
    int i = blockIdx.x * 256 + t;
    int v = (i < N_NODES) ? hist[i] : 0;
    __shared__ int sd[256];
    sd[t] = v;
    __syncthreads();
    #pragma unroll
    for (int ofs = 1; ofs < 256; ofs <<= 1) {
        int u = (t >= ofs) ? sd[t - ofs] : 0;
        __syncthreads();
        sd[t] += u;
        __syncthreads();
    }
    if (i < N_NODES) rowptr[i] = sd[t] - v;
    if (t == 255) bsum[blockIdx.x] = sd[255];
}

// phase 2+3 fused: each block sums bsum[0..blockIdx) itself, adds to rowptr
__global__ __launch_bounds__(256) void scan3_kernel(int* __restrict__ rowptr,
                                                    const int* __restrict__ bsum,
                                                    int* __restrict__ off)
{
    int t = threadIdx.x;
    int v = (t < (int)blockIdx.x) ? bsum[t] : 0;   // blockIdx.x <= 195
    __shared__ int sd[256];
    sd[t] = v;
    __syncthreads();
    #pragma unroll
    for (int ofs = 1; ofs < 256; ofs <<= 1) {
        int u = (t >= ofs) ? sd[t - ofs] : 0;
        __syncthreads();
        sd[t] += u;
        __syncthreads();
    }
    int boff = sd[255];
    int i = blockIdx.x * 256 + t;
    if (i < N_NODES) {
        int r = rowptr[i] + boff;
        rowptr[i] = r;
        off[i] = r;
    }
}

__global__ __launch_bounds__(256) void scatter_kernel(const int* __restrict__ ei,
                                                      int* __restrict__ off,
                                                      int* __restrict__ src_csr)
{
    int t = blockIdx.x * 256 + threadIdx.x;
    if (t >= ET) return;
    int s, d;
    if (t < N_EDGES) { s = ei[t]; d = ei[N_EDGES + t]; } else { s = d = t - N_EDGES; }
    int pos = atomicAdd(&off[d], 1);
    src_csr[pos] = s;
}

// ---------------- fused layer-1 linear: X staged once, W direct from L2 -----
// One barrier total; B-fragments loaded global->reg (Wt is L2-resident).
__global__ __launch_bounds__(256) void lin1_fused_kernel(
    const u16* __restrict__ X, const u16* __restrict__ Wt,   // Wt: [2][256][128]
    const u16* __restrict__ bl, const u16* __restrict__ br,
    u16* __restrict__ Yl, u16* __restrict__ Yr, int nrows)
{
    constexpr int K = 128, N = 256, LS = K + 8;
    __shared__ __align__(16) u16 sX[64 * LS];
    const bool f32m = detect_f32((const unsigned*)X);
    const float* X32 = (const float*)X;
    const int row0 = blockIdx.x * 64;
    const int wave = threadIdx.x >> 6, lane = threadIdx.x & 63;
    const int quad = lane >> 4, l16 = lane & 15;

    for (int i = threadIdx.x * 8; i < 64 * K; i += 2048) {
        int r = i >> 7, c = i & 127;
        int gr = row0 + r;
        u16* dst = &sX[r * LS + c];
        if (f32m) {
            float4 v0 = make_float4(0.f, 0.f, 0.f, 0.f), v1 = v0;
            if (gr < nrows) {
                v0 = *(const float4*)&X32[(size_t)gr * K + c];
                v1 = *(const float4*)&X32[(size_t)gr * K + c + 4];
            }
            ushort4 p0, p1;
            p0.x = f2bf(v0.x); p0.y = f2bf(v0.y); p0.z = f2bf(v0.z); p0.w = f2bf(v0.w);
            p1.x = f2bf(v1.x); p1.y = f2bf(v1.y); p1.z = f2bf(v1.z); p1.w = f2bf(v1.w);
            *(ushort4*)dst = p0;
            *(ushort4*)(dst + 4) = p1;
        } else {
            uint4 v = {0u, 0u, 0u, 0u};
            if (gr < nrows) v = *(const uint4*)&X[(size_t)gr * K + c];
            *(uint4*)dst = v;
        }
    }
    __syncthreads();   // the only barrier

    // preload A-fragments for this wave's 16 rows (reused across all cols)
    short8 a[4];
    #pragma unroll
    for (int kk = 0; kk < 4; ++kk)
        a[kk] = *(const short8*)&sX[(wave * 16 + l16) * LS + kk * 32 + quad * 8];

    for (int side = 0; side < 2; ++side) {
        const u16* wbase = Wt + side * (N * K);
        const u16* bias  = side ? br : bl;
        u16* Y = side ? Yr : Yl;
        #pragma unroll
        for (int ch = 0; ch < 4; ++ch) {
            floatx4 acc0 = {0.f, 0.f, 0.f, 0.f}, acc1 = acc0, acc2 = acc0, acc3 = acc0;
            #pragma unroll
            for (int kk = 0; kk < 4; ++kk) {
                const size_t kb = (size_t)kk * 32 + quad * 8;
                short8 b0 = *(const short8*)&wbase[(size_t)(ch * 64 +  0 + l16) * K + kb];
                short8 b1 = *(const short8*)&wbase[(size_t)(ch * 64 + 16 + l16) * K + kb];
                short8 b2 = *(const short8*)&wbase[(size_t)(ch * 64 + 32 + l16) * K + kb];
                short8 b3 = *(const short8*)&wbase[(size_t)(ch * 64 + 48 + l16) * K + kb];
                acc0 = __builtin_amdgcn_mfma_f32_16x16x32_bf16(a[kk], b0, acc0, 0, 0, 0);
                acc1 = __builtin_amdgcn_mfma_f32_16x16x32_bf16(a[kk], b1, acc1, 0, 0, 0);
                acc2 = __builtin_amdgcn_mfma_f32_16x16x32_bf16(a[kk], b2, acc2, 0, 0, 0);
                acc3 = __builtin_amdgcn_mfma_f32_16x16x32_bf16(a[kk], b3, acc3, 0, 0, 0);
            }
            const int rbase = row0 + wave * 16 + quad * 4;
            #pragma unroll
            for (int cf = 0; cf < 4; ++cf) {
                const floatx4 av = (cf == 0) ? acc0 : (cf == 1) ? acc1 : (cf == 2) ? acc2 : acc3;
                const int col = ch * 64 + cf * 16 + l16;
                const float bv = bf2f(bias[col]);
                #pragma unroll
                for (int r = 0; r < 4; ++r) {
                    int row = rbase + r;
                    if (row < nrows) Y[(size_t)row * N + col] = f2bf(av[r] + bv);
                }
            }
        }
    }
}

// ---------------- fused layer-2 linear: X staged once, W direct from L2 -----
__global__ __launch_bounds__(256) void lin2_fused_kernel(
    const u16* __restrict__ X, const u16* __restrict__ Wt,   // Wt: [2][64][256]
    const u16* __restrict__ bl, const u16* __restrict__ br,
    u16* __restrict__ Yl, u16* __restrict__ Yr, int nrows)
{
    constexpr int K = 256, N = 64, LS = K + 8;
    __shared__ __align__(16) u16 sX[64 * LS];
    const int row0 = blockIdx.x * 64;
    const int wave = threadIdx.x >> 6, lane = threadIdx.x & 63;
    const int quad = lane >> 4, l16 = lane & 15;

    for (int i = threadIdx.x * 8; i < 64 * K; i += 2048) {
        int r = i >> 8, c = i & 255;
        int gr = row0 + r;
        uint4 v = {0u, 0u, 0u, 0u};
        if (gr < nrows) v = *(const uint4*)&X[(size_t)gr * K + c];
        *(uint4*)&sX[r * LS + c] = v;
    }
    __syncthreads();   // the only barrier

    for (int side = 0; side < 2; ++side) {
        const u16* wbase = Wt + side * (N * K);
        const u16* bias  = side ? br : bl;
        u16* Y = side ? Yr : Yl;
        floatx4 acc0 = {0.f, 0.f, 0.f, 0.f}, acc1 = acc0, acc2 = acc0, acc3 = acc0;
        #pragma unroll
        for (int kk = 0; kk < 8; ++kk) {
            const size_t kb = (size_t)kk * 32 + quad * 8;
            short8 a  = *(const short8*)&sX[(wave * 16 + l16) * LS + kk * 32 + quad * 8];
            short8 b0 = *(const short8*)&wbase[(size_t)( 0 + l16) * K + kb];
            short8 b1 = *(const short8*)&wbase[(size_t)(16 + l16) * K + kb];
            short8 b2 = *(const short8*)&wbase[(size_t)(32 + l16) * K + kb];
            short8 b3 = *(const short8*)&wbase[(size_t)(48 + l16) * K + kb];
            acc0 = __builtin_amdgcn_mfma_f32_16x16x32_bf16(a, b0, acc0, 0, 0, 0);
            acc1 = __builtin_amdgcn_mfma_f32_16x16x32_bf16(a, b1, acc1, 0, 0, 0);
            acc2 = __builtin_amdgcn_mfma_f32_16x16x32_bf16(a, b2, acc2, 0, 0, 0);
            acc3 = __builtin_amdgcn_mfma_f32_16x16x32_bf16(a, b3, acc3, 0, 0, 0);
        }
        const int rbase = row0 + wave * 16 + quad * 4;
        #pragma unroll
        for (int cf = 0; cf < 4; ++cf) {
            const floatx4 av = (cf == 0) ? acc0 : (cf == 1) ? acc1 : (cf == 2) ? acc2 : acc3;
            const int col = cf * 16 + l16;
            const float bv = bf2f(bias[col]);
            #pragma unroll
            for (int r = 0; r < 4; ++r) {
                int row = rbase + r;
                if (row < nrows) Y[(size_t)row * N + col] = f2bf(av[r] + bv);
            }
        }
    }
}

// ---------------- layer 1 fused per-node GATv2 (4 heads x 64 ch) ------------
__global__ __launch_bounds__(256) void node1_kernel(
    const u16* __restrict__ xl, const u16* __restrict__ xr,
    const int* __restrict__ rowptr, const int* __restrict__ hist,
    const int* __restrict__ src_csr, const u16* __restrict__ att,
    const u16* __restrict__ bias, u16* __restrict__ hout)
{
    const int d = __builtin_amdgcn_readfirstlane(blockIdx.x * 4 + (threadIdx.x >> 6));
    if (d >= N_NODES) return;
    const int l = threadIdx.x & 63;
    const int start = rowptr[d];
    const int deg = hist[d];

    uint2 auv = *(const uint2*)&att[l * 4];
    const f32x2 atA = up2(auv.x), atB = up2(auv.y);
    uint2 ruv = *(const uint2*)&xr[(size_t)d * C1 + l * 4];
    const f32x2 rA = up2(ruv.x), rB = up2(ruv.y);

    float m = -1e30f, la = 0.f;
    f32x2 accA = {0.f, 0.f}, accB = {0.f, 0.f};
    for (int j = 0; j < deg; j += 4) {
        const bool v1 = j + 1 < deg, v2 = j + 2 < deg, v3 = j + 3 < deg;
        int s0 = src_csr[start + j];
        int s1 = v1 ? src_csr[start + j + 1] : s0;
        int s2 = v2 ? src_csr[start + j + 2] : s0;
        int s3 = v3 ? src_csr[start + j + 3] : s0;
        uint2 u0 = *(const uint2*)&xl[(size_t)s0 * C1 + l * 4];
        uint2 u1 = *(const uint2*)&xl[(size_t)s1 * C1 + l * 4];
        uint2 u2 = *(const uint2*)&xl[(size_t)s2 * C1 + l * 4];
        uint2 u3 = *(const uint2*)&xl[(size_t)s3 * C1 + l * 4];
        f32x2 x0A = up2(u0.x), x0B = up2(u0.y);
        f32x2 x1A = up2(u1.x), x1B = up2(u1.y);
        f32x2 x2A = up2(u2.x), x2B = up2(u2.y);
        f32x2 x3A = up2(u3.x), x3B = up2(u3.y);
        f32x2 t, pv;
        t = x0A + rA; t = __builtin_elementwise_max(t, t * SLOPE); pv  = t * atA;
        t = x0B + rB; t = __builtin_elementwise_max(t, t * SLOPE); pv += t * atB;
        float p0 = pv.x + pv.y;
        t = x1A + rA; t = __builtin_elementwise_max(t, t * SLOPE); pv  = t * atA;
        t = x1B + rB; t = __builtin_elementwise_max(t, t * SLOPE); pv += t * atB;
        float p1 = pv.x + pv.y;
        t = x2A + rA; t = __builtin_elementwise_max(t, t * SLOPE); pv  = t * atA;
        t = x2B + rB; t = __builtin_elementwise_max(t, t * SLOPE); pv += t * atB;
        float p2 = pv.x + pv.y;
        t = x3A + rA; t = __builtin_elementwise_max(t, t * SLOPE); pv  = t * atA;
        t = x3B + rB; t = __builtin_elementwise_max(t, t * SLOPE); pv += t * atB;
        float p3 = pv.x + pv.y;
        p0 = red16(p0); p1 = red16(p1); p2 = red16(p2); p3 = red16(p3);
        float pm = p0;
        if (v1) pm = fmaxf(pm, p1);
        if (v2) pm = fmaxf(pm, p2);
        if (v3) pm = fmaxf(pm, p3);
        float mn = fmaxf(m, pm);
        float sc = __expf(m - mn);
        float w0 = __expf(p0 - mn);
        float w1 = v1 ? __expf(p1 - mn) : 0.f;
        float w2 = v2 ? __expf(p2 - mn) : 0.f;
        float w3 = v3 ? __expf(p3 - mn) : 0.f;
        la = la * sc + w0 + w1 + w2 + w3;
        accA = accA * sc + x0A * w0 + x1A * w1 + x2A * w2 + x3A * w3;
        accB = accB * sc + x0B * w0 + x1B * w1 + x2B * w2 + x3B * w3;
        m = mn;
    }
    const float inv = 1.f / la;
    const int c = l * 4;
    float v0 = accA.x * inv + bf2f(bias[c + 0]);
    float v1 = accA.y * inv + bf2f(bias[c + 1]);
    float v2 = accB.x * inv + bf2f(bias[c + 2]);
    float v3 = accB.y * inv + bf2f(bias[c + 3]);
    v0 = v0 > 0.f ? v0 : __expf(fminf(v0, 0.f)) - 1.f;
    v1 = v1 > 0.f ? v1 : __expf(fminf(v1, 0.f)) - 1.f;
    v2 = v2 > 0.f ? v2 : __expf(fminf(v2, 0.f)) - 1.f;
    v3 = v3 > 0.f ? v3 : __expf(fminf(v3, 0.f)) - 1.f;
    ushort4 o;
    o.x = f2bf(v0); o.y = f2bf(v1); o.z = f2bf(v2); o.w = f2bf(v3);
    *(ushort4*)&hout[(size_t)d * C1 + c] = o;
}

// ---------------- layer 2 fused per-node GATv2 (1 head x 64 ch) --------------
__global__ __launch_bounds__(256) void node2_kernel(
    const u16* __restrict__ xl, const u16* __restrict__ xr,
    const int* __restrict__ rowptr, const int* __restrict__ hist,
    const int* __restrict__ src_csr, const u16* __restrict__ att,
    const u16* __restrict__ bias, void* __restrict__ outp,
    const unsigned* __restrict__ xorig)
{
    const bool f32o = detect_f32(xorig);
    const int d = __builtin_amdgcn_readfirstlane(blockIdx.x * 4 + (threadIdx.x >> 6));
    if (d >= N_NODES) return;
    const int l = threadIdx.x & 63;
    const int start = rowptr[d];
    const int deg = hist[d];
    const int g = l >> 4, sub = l & 15;
    const int c0 = sub * 4;

    uint2 auv = *(const uint2*)&att[c0];
    const f32x2 atA = up2(auv.x), atB = up2(auv.y);
    uint2 ruv = *(const uint2*)&xr[(size_t)d * OUTC + c0];
    const f32x2 rA = up2(ruv.x), rB = up2(ruv.y);

    float m = -1e30f, la = 0.f;
    f32x2 accA = {0.f, 0.f}, accB = {0.f, 0.f};
    for (int j = 0; j < deg; j += 4) {
        const bool valid = j + g < deg;
        int s = valid ? src_csr[start + j + g] : d;
        uint2 uv = *(const uint2*)&xl[(size_t)s * OUTC + c0];
        f32x2 xA = up2(uv.x), xB = up2(uv.y);
        f32x2 t, pv;
        t = xA + rA; t = __builtin_elementwise_max(t, t * SLOPE); pv  = t * atA;
        t = xB + rB; t = __builtin_elementwise_max(t, t * SLOPE); pv += t * atB;
        float p = pv.x + pv.y;
        p = red16(p);
        float pvv = valid ? p : -1e30f;
        float mn = fmaxf(m, pvv);
        float sc = __expf(m - mn);
        float w  = valid ? __expf(p - mn) : 0.f;
        la = la * sc + w;
        accA = accA * sc + xA * w;
        accB = accB * sc + xB * w;
        m = mn;
    }
    // merge the 4 groups' online-softmax states (xor 16, then 32)
    #pragma unroll
    for (int ofs = 16; ofs <= 32; ofs <<= 1) {
        float mo = __shfl_xor(m, ofs);
        float lo = __shfl_xor(la, ofs);
        float bax = __shfl_xor(accA.x, ofs);
        float bay = __shfl_xor(accA.y, ofs);
        float bbx = __shfl_xor(accB.x, ofs);
        float bby = __shfl_xor(accB.y, ofs);
        float mn = fmaxf(m, mo);
        float s0 = __expf(m - mn), s1 = __expf(mo - mn);
        la = la * s0 + lo * s1;
        accA.x = accA.x * s0 + bax * s1;
        accA.y = accA.y * s0 + bay * s1;
        accB.x = accB.x * s0 + bbx * s1;
        accB.y = accB.y * s0 + bby * s1;
        m = mn;
    }
    if (g == 0) {
        const float inv = 1.f / la;
        float v0 = accA.x * inv + bf2f(bias[c0 + 0]);
        float v1 = accA.y * inv + bf2f(bias[c0 + 1]);
        float v2 = accB.x * inv + bf2f(bias[c0 + 2]);
        float v3 = accB.y * inv + bf2f(bias[c0 + 3]);
        if (f32o) {
            float4 o = make_float4(v0, v1, v2, v3);
            *(float4*)&((float*)outp)[(size_t)d * OUTC + c0] = o;
        } else {
            ushort4 o;
            o.x = f2bf(v0); o.y = f2bf(v1); o.z = f2bf(v2); o.w = f2bf(v3);
            *(ushort4*)&((u16*)outp)[(size_t)d * OUTC + c0] = o;
        }
    }
}

extern "C" void kernel_launch(void* const* d_in, const int* in_sizes, int n_in,
                              void* d_out, int out_size, void* d_ws, size_t ws_size,
                              hipStream_t stream)
{
    const void* x  = d_in[0];
    const int*  ei = (const int*)d_in[1];

    char* ws = (char*)d_ws;
    u16* xl1     = (u16*)(ws + 0);          // 25.6 MB
    u16* xr1     = (u16*)(ws + 25600000);   // 25.6 MB
    u16* hbuf    = (u16*)(ws + 51200000);   // 25.6 MB
    u16* xl2     = (u16*)(ws + 0);          // overlay xl1 (dead after node1)
    u16* xr2     = (u16*)(ws + 6400000);
    int* hist    = (int*)(ws + 76800000);
    int* rowptr  = (int*)(ws + 77000000);
    int* off     = (int*)(ws + 77200000);
    int* src_csr = (int*)(ws + 77400000);   // 1.8 MB
    u16* prm     = (u16*)(ws + 79200064);   // 1280 u16 small params
    u16* wt      = (u16*)(ws + 79210240);   // 98304 u16 transposed weights
    int* bsum    = (int*)(ws + 79410000);

    u16* bl1   = prm + 0;
    u16* br1   = prm + 256;
    u16* att1  = prm + 512;
    u16* bias1 = prm + 768;
    u16* bl2   = prm + 1024;
    u16* br2   = prm + 1088;
    u16* att2  = prm + 1152;
    u16* bias2 = prm + 1216;
    u16* wt1   = wt + 0;       // [2][256][128]
    u16* wt2   = wt + 65536;   // [2][64][256]

    convert_all_kernel<<<581, 256, 0, stream>>>(
        (const unsigned*)x,
        d_in[2], d_in[4], d_in[8], d_in[10],
        d_in[3], d_in[5], d_in[6], d_in[7], d_in[9], d_in[11], d_in[12], d_in[13],
        wt, prm, hist);

    const int eb = (ET + 255) / 256;
    hist_kernel<<<eb, 256, 0, stream>>>(ei, hist);
    scan1_kernel<<<196, 256, 0, stream>>>(hist, rowptr, bsum);
    scan3_kernel<<<196, 256, 0, stream>>>(rowptr, bsum, off);
    scatter_kernel<<<eb, 256, 0, stream>>>(ei, off, src_csr);

    const int gb = (N_NODES + 63) / 64;   // 782
    lin1_fused_kernel<<<gb, 256, 0, stream>>>((const u16*)x, wt1, bl1, br1, xl1, xr1, N_NODES);
    const int nb = (N_NODES * 64 + 255) / 256;   // 12500 blocks, 4 waves each
    node1_kernel<<<nb, 256, 0, stream>>>(xl1, xr1, rowptr, hist, src_csr, att1, bias1, hbuf);
    lin2_fused_kernel<<<gb, 256, 0, stream>>>(hbuf, wt2, bl2, br2, xl2, xr2, N_NODES);
    node2_kernel<<<nb, 256, 0, stream>>>(xl2, xr2, rowptr, hist, src_csr, att2, bias2, d_out,
                                         (const unsigned*)x);
}

// Round 13
// 266.180 us; speedup vs baseline: 1.1920x; 1.1920x over previous
//
#include <hip/hip_runtime.h>
#include <hip/hip_bf16.h>

typedef unsigned short u16;
typedef __attribute__((ext_vector_type(8))) short short8;
typedef __attribute__((ext_vector_type(4))) float floatx4;
typedef __attribute__((ext_vector_type(2))) float f32x2;

#define N_NODES 50000
#define N_EDGES 400000
#define ET      450000   // edges + self loops
#define F_IN    128
#define C1      256      // H*HID
#define HID     64
#define OUTC    64
#define SLOPE   0.2f

__device__ __forceinline__ float bf2f(u16 v) {
    return __uint_as_float(((unsigned)v) << 16);
}
__device__ __forceinline__ float bflo(unsigned u) { return __uint_as_float(u << 16); }
__device__ __forceinline__ float bfhi(unsigned u) { return __uint_as_float(u & 0xffff0000u); }
__device__ __forceinline__ u16 f2bf(float f) {   // round-to-nearest-even
    unsigned u = __float_as_uint(f);
    return (u16)((u + 0x7fffu + ((u >> 16) & 1u)) >> 16);
}
__device__ __forceinline__ f32x2 up2(unsigned u) {
    f32x2 r; r.x = bflo(u); r.y = bfhi(u); return r;
}
// single-instruction cross-lane add via DPP (no LDS, no lgkm wait)
template<int CTRL>
__device__ __forceinline__ float dpp_add(float x) {
    return x + __int_as_float(__builtin_amdgcn_update_dpp(
        0, __float_as_int(x), CTRL, 0xF, 0xF, true));
}
// reduce over 16-lane group: xor1, xor2, mirror-8, mirror-16
__device__ __forceinline__ float red16(float p) {
    p = dpp_add<0xB1>(p);
    p = dpp_add<0x4E>(p);
    p = dpp_add<0x141>(p);
    p = dpp_add<0x140>(p);
    return p;
}
// inline dtype detection: wave-ballot over first 64 words of x.
__device__ __forceinline__ bool detect_f32(const unsigned* __restrict__ xw) {
    unsigned w = xw[threadIdx.x & 63];
    unsigned aexp = (w >> 7) & 0xFFu;
    unsigned long long b = __ballot(aexp >= 170u || aexp <= 40u);
    return __popcll(b) >= 16;
}

// ---------------- fused param convert + hist zero ---------------------------
__global__ __launch_bounds__(256) void convert_all_kernel(
    const unsigned* __restrict__ xw,
    const void* wl1, const void* wr1, const void* wl2, const void* wr2,
    const void* s0, const void* s1, const void* s2, const void* s3,
    const void* s4, const void* s5, const void* s6, const void* s7,
    u16* __restrict__ wt, u16* __restrict__ prm, int* __restrict__ hist)
{
    if (blockIdx.x >= 385) {
        int idx = (blockIdx.x - 385) * 256 + threadIdx.x;
        if (idx < N_NODES) hist[idx] = 0;
        return;
    }
    bool f32m = detect_f32(xw);
    if (blockIdx.x == 384) {
        for (int t = threadIdx.x; t < 1280; t += 256) {
            const void* src; int local;
            if      (t < 256)  { src = s0; local = t; }
            else if (t < 512)  { src = s1; local = t - 256; }
            else if (t < 768)  { src = s2; local = t - 512; }
            else if (t < 1024) { src = s3; local = t - 768; }
            else if (t < 1088) { src = s4; local = t - 1024; }
            else if (t < 1152) { src = s5; local = t - 1088; }
            else if (t < 1216) { src = s6; local = t - 1152; }
            else               { src = s7; local = t - 1216; }
            prm[t] = f32m ? f2bf(((const float*)src)[local]) : ((const u16*)src)[local];
        }
        return;
    }
    int t = blockIdx.x * 256 + threadIdx.x;   // 98304 total
    const void* src; int local, k, n, K, base;
    if (t < 32768)      { src = wl1; local = t;         k = local >> 8; n = local & 255; K = 128; base = 0; }
    else if (t < 65536) { src = wr1; local = t - 32768; k = local >> 8; n = local & 255; K = 128; base = 32768; }
    else if (t < 81920) { src = wl2; local = t - 65536; k = local >> 6; n = local & 63;  K = 256; base = 65536; }
    else                { src = wr2; local = t - 81920; k = local >> 6; n = local & 63;  K = 256; base = 81920; }
    u16 v = f32m ? f2bf(((const float*)src)[local]) : ((const u16*)src)[local];
    wt[base + n * K + k] = v;
}

// ---------------- CSR build (by dst) ----------------
__global__ __launch_bounds__(256) void hist_kernel(const int* __restrict__ ei,
                                                   int* __restrict__ hist)
{
    int t = blockIdx.x * 256 + threadIdx.x;
    if (t >= ET) return;
    int d = (t < N_EDGES) ? ei[N_EDGES + t] : t - N_EDGES;
    atomicAdd(&hist[d], 1);
}

__global__ __launch_bounds__(256) void scan1_kernel(const int* __restrict__ hist,
                                                    int* __restrict__ rowptr,
                                                    int* __restrict__ bsum)
{
    int t = threadIdx.x;
    int i = blockIdx.x * 256 + t;
    int v = (i < N_NODES) ? hist[i] : 0;
    __shared__ int sd[256];
    sd[t] = v;
    __syncthreads();
    #pragma unroll
    for (int ofs = 1; ofs < 256; ofs <<= 1) {
        int u = (t >= ofs) ? sd[t - ofs] : 0;
        __syncthreads();
        sd[t] += u;
        __syncthreads();
    }
    if (i < N_NODES) rowptr[i] = sd[t] - v;
    if (t == 255) bsum[blockIdx.x] = sd[255];
}

// phase 2+3 fused: each block sums bsum[0..blockIdx) itself, adds to rowptr
__global__ __launch_bounds__(256) void scan3_kernel(int* __restrict__ rowptr,
                                                    const int* __restrict__ bsum,
                                                    int* __restrict__ off)
{
    int t = threadIdx.x;
    int v = (t < (int)blockIdx.x) ? bsum[t] : 0;   // blockIdx.x <= 195
    __shared__ int sd[256];
    sd[t] = v;
    __syncthreads();
    #pragma unroll
    for (int ofs = 1; ofs < 256; ofs <<= 1) {
        int u = (t >= ofs) ? sd[t - ofs] : 0;
        __syncthreads();
        sd[t] += u;
        __syncthreads();
    }
    int boff = sd[255];
    int i = blockIdx.x * 256 + t;
    if (i < N_NODES) {
        int r = rowptr[i] + boff;
        rowptr[i] = r;
        off[i] = r;
    }
}

__global__ __launch_bounds__(256) void scatter_kernel(const int* __restrict__ ei,
                                                      int* __restrict__ off,
                                                      int* __restrict__ src_csr)
{
    int t = blockIdx.x * 256 + threadIdx.x;
    if (t >= ET) return;
    int s, d;
    if (t < N_EDGES) { s = ei[t]; d = ei[N_EDGES + t]; } else { s = d = t - N_EDGES; }
    int pos = atomicAdd(&off[d], 1);
    src_csr[pos] = s;
}

// ---------------- fused layer-1 linear (R11 LDS-staged form) ----------------
__global__ __launch_bounds__(256) void lin1_fused_kernel(
    const u16* __restrict__ X, const u16* __restrict__ Wt,   // Wt: [2][256][128]
    const u16* __restrict__ bl, const u16* __restrict__ br,
    u16* __restrict__ Yl, u16* __restrict__ Yr, int nrows)
{
    constexpr int K = 128, N = 256, LS = K + 8;
    __shared__ __align__(16) u16 sX[64 * LS];
    __shared__ __align__(16) u16 sW[64 * LS];
    const bool f32m = detect_f32((const unsigned*)X);
    const float* X32 = (const float*)X;
    const int row0 = blockIdx.x * 64;
    const int wave = threadIdx.x >> 6, lane = threadIdx.x & 63;
    const int quad = lane >> 4, l16 = lane & 15;

    for (int i = threadIdx.x * 8; i < 64 * K; i += 2048) {
        int r = i >> 7, c = i & 127;
        int gr = row0 + r;
        u16* dst = &sX[r * LS + c];
        if (f32m) {
            float4 v0 = make_float4(0.f, 0.f, 0.f, 0.f), v1 = v0;
            if (gr < nrows) {
                v0 = *(const float4*)&X32[(size_t)gr * K + c];
                v1 = *(const float4*)&X32[(size_t)gr * K + c + 4];
            }
            ushort4 p0, p1;
            p0.x = f2bf(v0.x); p0.y = f2bf(v0.y); p0.z = f2bf(v0.z); p0.w = f2bf(v0.w);
            p1.x = f2bf(v1.x); p1.y = f2bf(v1.y); p1.z = f2bf(v1.z); p1.w = f2bf(v1.w);
            *(ushort4*)dst = p0;
            *(ushort4*)(dst + 4) = p1;
        } else {
            uint4 v = {0u, 0u, 0u, 0u};
            if (gr < nrows) v = *(const uint4*)&X[(size_t)gr * K + c];
            *(uint4*)dst = v;
        }
    }
    __syncthreads();

    // preload A-fragments once (reused across all 8 col rounds)
    short8 a[4];
    #pragma unroll
    for (int kk = 0; kk < 4; ++kk)
        a[kk] = *(const short8*)&sX[(wave * 16 + l16) * LS + kk * 32 + quad * 8];

    for (int side = 0; side < 2; ++side) {
        const u16* wbase = Wt + side * (N * K);
        const u16* bias  = side ? br : bl;
        u16* Y = side ? Yr : Yl;
        for (int ch = 0; ch < 4; ++ch) {
            __syncthreads();   // protect sW from previous round's readers
            for (int i = threadIdx.x * 8; i < 64 * K; i += 2048) {
                int n = i >> 7, c = i & 127;
                *(uint4*)&sW[n * LS + c] = *(const uint4*)&wbase[(size_t)(ch * 64 + n) * K + c];
            }
            __syncthreads();
            floatx4 acc0 = {0.f, 0.f, 0.f, 0.f}, acc1 = acc0, acc2 = acc0, acc3 = acc0;
            #pragma unroll
            for (int kk = 0; kk < 4; ++kk) {
                short8 b0 = *(const short8*)&sW[(l16) * LS + kk * 32 + quad * 8];
                short8 b1 = *(const short8*)&sW[(16 + l16) * LS + kk * 32 + quad * 8];
                short8 b2 = *(const short8*)&sW[(32 + l16) * LS + kk * 32 + quad * 8];
                short8 b3 = *(const short8*)&sW[(48 + l16) * LS + kk * 32 + quad * 8];
                acc0 = __builtin_amdgcn_mfma_f32_16x16x32_bf16(a[kk], b0, acc0, 0, 0, 0);
                acc1 = __builtin_amdgcn_mfma_f32_16x16x32_bf16(a[kk], b1, acc1, 0, 0, 0);
                acc2 = __builtin_amdgcn_mfma_f32_16x16x32_bf16(a[kk], b2, acc2, 0, 0, 0);
                acc3 = __builtin_amdgcn_mfma_f32_16x16x32_bf16(a[kk], b3, acc3, 0, 0, 0);
            }
            const int rbase = row0 + wave * 16 + quad * 4;
            #pragma unroll
            for (int cf = 0; cf < 4; ++cf) {
                const floatx4 av = (cf == 0) ? acc0 : (cf == 1) ? acc1 : (cf == 2) ? acc2 : acc3;
                const int col = ch * 64 + cf * 16 + l16;
                const float bv = bf2f(bias[col]);
                #pragma unroll
                for (int r = 0; r < 4; ++r) {
                    int row = rbase + r;
                    if (row < nrows) Y[(size_t)row * N + col] = f2bf(av[r] + bv);
                }
            }
        }
    }
}

// ---------------- fused layer-2 linear (R11 LDS-staged form) ----------------
__global__ __launch_bounds__(256) void lin2_fused_kernel(
    const u16* __restrict__ X, const u16* __restrict__ Wt,   // Wt: [2][64][256]
    const u16* __restrict__ bl, const u16* __restrict__ br,
    u16* __restrict__ Yl, u16* __restrict__ Yr, int nrows)
{
    constexpr int K = 256, N = 64, LS = K + 8;
    __shared__ __align__(16) u16 sX[64 * LS];
    __shared__ __align__(16) u16 sW[64 * LS];
    const int row0 = blockIdx.x * 64;
    const int wave = threadIdx.x >> 6, lane = threadIdx.x & 63;
    const int quad = lane >> 4, l16 = lane & 15;

    for (int i = threadIdx.x * 8; i < 64 * K; i += 2048) {
        int r = i >> 8, c = i & 255;
        int gr = row0 + r;
        uint4 v = {0u, 0u, 0u, 0u};
        if (gr < nrows) v = *(const uint4*)&X[(size_t)gr * K + c];
        *(uint4*)&sX[r * LS + c] = v;
    }
    __syncthreads();

    short8 a[8];
    #pragma unroll
    for (int kk = 0; kk < 8; ++kk)
        a[kk] = *(const short8*)&sX[(wave * 16 + l16) * LS + kk * 32 + quad * 8];

    for (int side = 0; side < 2; ++side) {
        const u16* wbase = Wt + side * (N * K);
        const u16* bias  = side ? br : bl;
        u16* Y = side ? Yr : Yl;
        __syncthreads();
        for (int i = threadIdx.x * 8; i < 64 * K; i += 2048) {
            int n = i >> 8, c = i & 255;
            *(uint4*)&sW[n * LS + c] = *(const uint4*)&wbase[(size_t)n * K + c];
        }
        __syncthreads();
        floatx4 acc0 = {0.f, 0.f, 0.f, 0.f}, acc1 = acc0, acc2 = acc0, acc3 = acc0;
        #pragma unroll
        for (int kk = 0; kk < 8; ++kk) {
            short8 b0 = *(const short8*)&sW[(l16) * LS + kk * 32 + quad * 8];
            short8 b1 = *(const short8*)&sW[(16 + l16) * LS + kk * 32 + quad * 8];
            short8 b2 = *(const short8*)&sW[(32 + l16) * LS + kk * 32 + quad * 8];
            short8 b3 = *(const short8*)&sW[(48 + l16) * LS + kk * 32 + quad * 8];
            acc0 = __builtin_amdgcn_mfma_f32_16x16x32_bf16(a[kk], b0, acc0, 0, 0, 0);
            acc1 = __builtin_amdgcn_mfma_f32_16x16x32_bf16(a[kk], b1, acc1, 0, 0, 0);
            acc2 = __builtin_amdgcn_mfma_f32_16x16x32_bf16(a[kk], b2, acc2, 0, 0, 0);
            acc3 = __builtin_amdgcn_mfma_f32_16x16x32_bf16(a[kk], b3, acc3, 0, 0, 0);
        }
        const int rbase = row0 + wave * 16 + quad * 4;
        #pragma unroll
        for (int cf = 0; cf < 4; ++cf) {
            const floatx4 av = (cf == 0) ? acc0 : (cf == 1) ? acc1 : (cf == 2) ? acc2 : acc3;
            const int col = cf * 16 + l16;
            const float bv = bf2f(bias[col]);
            #pragma unroll
            for (int r = 0; r < 4; ++r) {
                int row = rbase + r;
                if (row < nrows) Y[(size_t)row * N + col] = f2bf(av[r] + bv);
            }
        }
    }
}

// ---------------- layer 1 fused per-node GATv2 (4 heads x 64 ch) ------------
// split into two half-grid dispatches (d0 offset) for profiling visibility.
__global__ __launch_bounds__(256) void node1_kernel(
    const u16* __restrict__ xl, const u16* __restrict__ xr,
    const int* __restrict__ rowptr, const int* __restrict__ hist,
    const int* __restrict__ src_csr, const u16* __restrict__ att,
    const u16* __restrict__ bias, u16* __restrict__ hout, int d0)
{
    const int d = __builtin_amdgcn_readfirstlane(d0 + blockIdx.x * 4 + (threadIdx.x >> 6));
    if (d >= N_NODES) return;
    const int l = threadIdx.x & 63;
    const int start = rowptr[d];
    const int deg = hist[d];

    uint2 auv = *(const uint2*)&att[l * 4];
    const f32x2 atA = up2(auv.x), atB = up2(auv.y);
    uint2 ruv = *(const uint2*)&xr[(size_t)d * C1 + l * 4];
    const f32x2 rA = up2(ruv.x), rB = up2(ruv.y);

    float m = -1e30f, la = 0.f;
    f32x2 accA = {0.f, 0.f}, accB = {0.f, 0.f};
    for (int j = 0; j < deg; j += 4) {
        const bool v1 = j + 1 < deg, v2 = j + 2 < deg, v3 = j + 3 < deg;
        int s0 = src_csr[start + j];
        int s1 = v1 ? src_csr[start + j + 1] : s0;
        int s2 = v2 ? src_csr[start + j + 2] : s0;
        int s3 = v3 ? src_csr[start + j + 3] : s0;
        uint2 u0 = *(const uint2*)&xl[(size_t)s0 * C1 + l * 4];
        uint2 u1 = *(const uint2*)&xl[(size_t)s1 * C1 + l * 4];
        uint2 u2 = *(const uint2*)&xl[(size_t)s2 * C1 + l * 4];
        uint2 u3 = *(const uint2*)&xl[(size_t)s3 * C1 + l * 4];
        f32x2 x0A = up2(u0.x), x0B = up2(u0.y);
        f32x2 x1A = up2(u1.x), x1B = up2(u1.y);
        f32x2 x2A = up2(u2.x), x2B = up2(u2.y);
        f32x2 x3A = up2(u3.x), x3B = up2(u3.y);
        f32x2 t, pv;
        t = x0A + rA; t = __builtin_elementwise_max(t, t * SLOPE); pv  = t * atA;
        t = x0B + rB; t = __builtin_elementwise_max(t, t * SLOPE); pv += t * atB;
        float p0 = pv.x + pv.y;
        t = x1A + rA; t = __builtin_elementwise_max(t, t * SLOPE); pv  = t * atA;
        t = x1B + rB; t = __builtin_elementwise_max(t, t * SLOPE); pv += t * atB;
        float p1 = pv.x + pv.y;
        t = x2A + rA; t = __builtin_elementwise_max(t, t * SLOPE); pv  = t * atA;
        t = x2B + rB; t = __builtin_elementwise_max(t, t * SLOPE); pv += t * atB;
        float p2 = pv.x + pv.y;
        t = x3A + rA; t = __builtin_elementwise_max(t, t * SLOPE); pv  = t * atA;
        t = x3B + rB; t = __builtin_elementwise_max(t, t * SLOPE); pv += t * atB;
        float p3 = pv.x + pv.y;
        p0 = red16(p0); p1 = red16(p1); p2 = red16(p2); p3 = red16(p3);
        float pm = p0;
        if (v1) pm = fmaxf(pm, p1);
        if (v2) pm = fmaxf(pm, p2);
        if (v3) pm = fmaxf(pm, p3);
        float mn = fmaxf(m, pm);
        float sc = __expf(m - mn);
        float w0 = __expf(p0 - mn);
        float w1 = v1 ? __expf(p1 - mn) : 0.f;
        float w2 = v2 ? __expf(p2 - mn) : 0.f;
        float w3 = v3 ? __expf(p3 - mn) : 0.f;
        la = la * sc + w0 + w1 + w2 + w3;
        accA = accA * sc + x0A * w0 + x1A * w1 + x2A * w2 + x3A * w3;
        accB = accB * sc + x0B * w0 + x1B * w1 + x2B * w2 + x3B * w3;
        m = mn;
    }
    const float inv = 1.f / la;
    const int c = l * 4;
    float v0 = accA.x * inv + bf2f(bias[c + 0]);
    float v1 = accA.y * inv + bf2f(bias[c + 1]);
    float v2 = accB.x * inv + bf2f(bias[c + 2]);
    float v3 = accB.y * inv + bf2f(bias[c + 3]);
    v0 = v0 > 0.f ? v0 : __expf(fminf(v0, 0.f)) - 1.f;
    v1 = v1 > 0.f ? v1 : __expf(fminf(v1, 0.f)) - 1.f;
    v2 = v2 > 0.f ? v2 : __expf(fminf(v2, 0.f)) - 1.f;
    v3 = v3 > 0.f ? v3 : __expf(fminf(v3, 0.f)) - 1.f;
    ushort4 o;
    o.x = f2bf(v0); o.y = f2bf(v1); o.z = f2bf(v2); o.w = f2bf(v3);
    *(ushort4*)&hout[(size_t)d * C1 + c] = o;
}

// ---------------- layer 2 fused per-node GATv2 (1 head x 64 ch) --------------
__global__ __launch_bounds__(256) void node2_kernel(
    const u16* __restrict__ xl, const u16* __restrict__ xr,
    const int* __restrict__ rowptr, const int* __restrict__ hist,
    const int* __restrict__ src_csr, const u16* __restrict__ att,
    const u16* __restrict__ bias, void* __restrict__ outp,
    const unsigned* __restrict__ xorig)
{
    const bool f32o = detect_f32(xorig);
    const int d = __builtin_amdgcn_readfirstlane(blockIdx.x * 4 + (threadIdx.x >> 6));
    if (d >= N_NODES) return;
    const int l = threadIdx.x & 63;
    const int start = rowptr[d];
    const int deg = hist[d];
    const int g = l >> 4, sub = l & 15;
    const int c0 = sub * 4;

    uint2 auv = *(const uint2*)&att[c0];
    const f32x2 atA = up2(auv.x), atB = up2(auv.y);
    uint2 ruv = *(const uint2*)&xr[(size_t)d * OUTC + c0];
    const f32x2 rA = up2(ruv.x), rB = up2(ruv.y);

    float m = -1e30f, la = 0.f;
    f32x2 accA = {0.f, 0.f}, accB = {0.f, 0.f};
    for (int j = 0; j < deg; j += 4) {
        const bool valid = j + g < deg;
        int s = valid ? src_csr[start + j + g] : d;
        uint2 uv = *(const uint2*)&xl[(size_t)s * OUTC + c0];
        f32x2 xA = up2(uv.x), xB = up2(uv.y);
        f32x2 t, pv;
        t = xA + rA; t = __builtin_elementwise_max(t, t * SLOPE); pv  = t * atA;
        t = xB + rB; t = __builtin_elementwise_max(t, t * SLOPE); pv += t * atB;
        float p = pv.x + pv.y;
        p = red16(p);
        float pvv = valid ? p : -1e30f;
        float mn = fmaxf(m, pvv);
        float sc = __expf(m - mn);
        float w  = valid ? __expf(p - mn) : 0.f;
        la = la * sc + w;
        accA = accA * sc + xA * w;
        accB = accB * sc + xB * w;
        m = mn;
    }
    #pragma unroll
    for (int ofs = 16; ofs <= 32; ofs <<= 1) {
        float mo = __shfl_xor(m, ofs);
        float lo = __shfl_xor(la, ofs);
        float bax = __shfl_xor(accA.x, ofs);
        float bay = __shfl_xor(accA.y, ofs);
        float bbx = __shfl_xor(accB.x, ofs);
        float bby = __shfl_xor(accB.y, ofs);
        float mn = fmaxf(m, mo);
        float s0 = __expf(m - mn), s1 = __expf(mo - mn);
        la = la * s0 + lo * s1;
        accA.x = accA.x * s0 + bax * s1;
        accA.y = accA.y * s0 + bay * s1;
        accB.x = accB.x * s0 + bbx * s1;
        accB.y = accB.y * s0 + bby * s1;
        m = mn;
    }
    if (g == 0) {
        const float inv = 1.f / la;
        float v0 = accA.x * inv + bf2f(bias[c0 + 0]);
        float v1 = accA.y * inv + bf2f(bias[c0 + 1]);
        float v2 = accB.x * inv + bf2f(bias[c0 + 2]);
        float v3 = accB.y * inv + bf2f(bias[c0 + 3]);
        if (f32o) {
            float4 o = make_float4(v0, v1, v2, v3);
            *(float4*)&((float*)outp)[(size_t)d * OUTC + c0] = o;
        } else {
            ushort4 o;
            o.x = f2bf(v0); o.y = f2bf(v1); o.z = f2bf(v2); o.w = f2bf(v3);
            *(ushort4*)&((u16*)outp)[(size_t)d * OUTC + c0] = o;
        }
    }
}

extern "C" void kernel_launch(void* const* d_in, const int* in_sizes, int n_in,
                              void* d_out, int out_size, void* d_ws, size_t ws_size,
                              hipStream_t stream)
{
    const void* x  = d_in[0];
    const int*  ei = (const int*)d_in[1];

    char* ws = (char*)d_ws;
    u16* xl1     = (u16*)(ws + 0);          // 25.6 MB
    u16* xr1     = (u16*)(ws + 25600000);   // 25.6 MB
    u16* hbuf    = (u16*)(ws + 51200000);   // 25.6 MB
    u16* xl2     = (u16*)(ws + 0);          // overlay xl1 (dead after node1)
    u16* xr2     = (u16*)(ws + 6400000);
    int* hist    = (int*)(ws + 76800000);
    int* rowptr  = (int*)(ws + 77000000);
    int* off     = (int*)(ws + 77200000);
    int* src_csr = (int*)(ws + 77400000);   // 1.8 MB
    u16* prm     = (u16*)(ws + 79200064);   // 1280 u16 small params
    u16* wt      = (u16*)(ws + 79210240);   // 98304 u16 transposed weights
    int* bsum    = (int*)(ws + 79410000);

    u16* bl1   = prm + 0;
    u16* br1   = prm + 256;
    u16* att1  = prm + 512;
    u16* bias1 = prm + 768;
    u16* bl2   = prm + 1024;
    u16* br2   = prm + 1088;
    u16* att2  = prm + 1152;
    u16* bias2 = prm + 1216;
    u16* wt1   = wt + 0;       // [2][256][128]
    u16* wt2   = wt + 65536;   // [2][64][256]

    convert_all_kernel<<<581, 256, 0, stream>>>(
        (const unsigned*)x,
        d_in[2], d_in[4], d_in[8], d_in[10],
        d_in[3], d_in[5], d_in[6], d_in[7], d_in[9], d_in[11], d_in[12], d_in[13],
        wt, prm, hist);

    const int eb = (ET + 255) / 256;
    hist_kernel<<<eb, 256, 0, stream>>>(ei, hist);
    scan1_kernel<<<196, 256, 0, stream>>>(hist, rowptr, bsum);
    scan3_kernel<<<196, 256, 0, stream>>>(rowptr, bsum, off);
    scatter_kernel<<<eb, 256, 0, stream>>>(ei, off, src_csr);

    const int gb = (N_NODES + 63) / 64;   // 782
    lin1_fused_kernel<<<gb, 256, 0, stream>>>((const u16*)x, wt1, bl1, br1, xl1, xr1, N_NODES);
    // node1 split into two half-grids (diagnostic: reveals #2 kernel in top-5)
    const int nbh = 6250;   // 25000 nodes per dispatch
    node1_kernel<<<nbh, 256, 0, stream>>>(xl1, xr1, rowptr, hist, src_csr, att1, bias1, hbuf, 0);
    node1_kernel<<<nbh, 256, 0, stream>>>(xl1, xr1, rowptr, hist, src_csr, att1, bias1, hbuf, 25000);
    lin2_fused_kernel<<<gb, 256, 0, stream>>>(hbuf, wt2, bl2, br2, xl2, xr2, N_NODES);
    node2_kernel<<<(N_NODES * 64 + 255) / 256, 256, 0, stream>>>(
        xl2, xr2, rowptr, hist, src_csr, att2, bias2, d_out, (const unsigned*)x);
}

// Round 14
// 251.660 us; speedup vs baseline: 1.2608x; 1.0577x over previous
//
#include <hip/hip_runtime.h>
#include <hip/hip_bf16.h>

typedef unsigned short u16;
typedef __attribute__((ext_vector_type(8))) short short8;
typedef __attribute__((ext_vector_type(4))) float floatx4;
typedef __attribute__((ext_vector_type(2))) float f32x2;

#define N_NODES 50000
#define N_EDGES 400000
#define ET      450000   // edges + self loops
#define F_IN    128
#define C1      256      // H*HID
#define HID     64
#define OUTC    64
#define SLOPE   0.2f
#define LIN1_BLOCKS 391  // ceil(50000/128)

__device__ __forceinline__ float bf2f(u16 v) {
    return __uint_as_float(((unsigned)v) << 16);
}
__device__ __forceinline__ float bflo(unsigned u) { return __uint_as_float(u << 16); }
__device__ __forceinline__ float bfhi(unsigned u) { return __uint_as_float(u & 0xffff0000u); }
__device__ __forceinline__ u16 f2bf(float f) {   // round-to-nearest-even
    unsigned u = __float_as_uint(f);
    return (u16)((u + 0x7fffu + ((u >> 16) & 1u)) >> 16);
}
__device__ __forceinline__ f32x2 up2(unsigned u) {
    f32x2 r; r.x = bflo(u); r.y = bfhi(u); return r;
}
template<int CTRL>
__device__ __forceinline__ float dpp_add(float x) {
    return x + __int_as_float(__builtin_amdgcn_update_dpp(
        0, __float_as_int(x), CTRL, 0xF, 0xF, true));
}
__device__ __forceinline__ float red16(float p) {
    p = dpp_add<0xB1>(p);
    p = dpp_add<0x4E>(p);
    p = dpp_add<0x141>(p);
    p = dpp_add<0x140>(p);
    return p;
}
__device__ __forceinline__ bool detect_f32(const unsigned* __restrict__ xw) {
    unsigned w = xw[threadIdx.x & 63];
    unsigned aexp = (w >> 7) & 0xFFu;
    unsigned long long b = __ballot(aexp >= 170u || aexp <= 40u);
    return __popcll(b) >= 16;
}

// ---------------- fused param convert + hist zero ---------------------------
__global__ __launch_bounds__(256) void convert_all_kernel(
    const unsigned* __restrict__ xw,
    const void* wl1, const void* wr1, const void* wl2, const void* wr2,
    const void* s0, const void* s1, const void* s2, const void* s3,
    const void* s4, const void* s5, const void* s6, const void* s7,
    u16* __restrict__ wt, u16* __restrict__ prm, int* __restrict__ hist)
{
    if (blockIdx.x >= 385) {
        int idx = (blockIdx.x - 385) * 256 + threadIdx.x;
        if (idx < N_NODES) hist[idx] = 0;
        return;
    }
    bool f32m = detect_f32(xw);
    if (blockIdx.x == 384) {
        for (int t = threadIdx.x; t < 1280; t += 256) {
            const void* src; int local;
            if      (t < 256)  { src = s0; local = t; }
            else if (t < 512)  { src = s1; local = t - 256; }
            else if (t < 768)  { src = s2; local = t - 512; }
            else if (t < 1024) { src = s3; local = t - 768; }
            else if (t < 1088) { src = s4; local = t - 1024; }
            else if (t < 1152) { src = s5; local = t - 1088; }
            else if (t < 1216) { src = s6; local = t - 1152; }
            else               { src = s7; local = t - 1216; }
            prm[t] = f32m ? f2bf(((const float*)src)[local]) : ((const u16*)src)[local];
        }
        return;
    }
    int t = blockIdx.x * 256 + threadIdx.x;   // 98304 total
    const void* src; int local, k, n, K, base;
    if (t < 32768)      { src = wl1; local = t;         k = local >> 8; n = local & 255; K = 128; base = 0; }
    else if (t < 65536) { src = wr1; local = t - 32768; k = local >> 8; n = local & 255; K = 128; base = 32768; }
    else if (t < 81920) { src = wl2; local = t - 65536; k = local >> 6; n = local & 63;  K = 256; base = 65536; }
    else                { src = wr2; local = t - 81920; k = local >> 6; n = local & 63;  K = 256; base = 81920; }
    u16 v = f32m ? f2bf(((const float*)src)[local]) : ((const u16*)src)[local];
    wt[base + n * K + k] = v;
}

// ---------------- CSR scan (phases) ----------------
__global__ __launch_bounds__(256) void scan1_kernel(const int* __restrict__ hist,
                                                    int* __restrict__ rowptr,
                                                    int* __restrict__ bsum)
{
    int t = threadIdx.x;
    int i = blockIdx.x * 256 + t;
    int v = (i < N_NODES) ? hist[i] : 0;
    __shared__ int sd[256];
    sd[t] = v;
    __syncthreads();
    #pragma unroll
    for (int ofs = 1; ofs < 256; ofs <<= 1) {
        int u = (t >= ofs) ? sd[t - ofs] : 0;
        __syncthreads();
        sd[t] += u;
        __syncthreads();
    }
    if (i < N_NODES) rowptr[i] = sd[t] - v;
    if (t == 255) bsum[blockIdx.x] = sd[255];
}

__global__ __launch_bounds__(256) void scan3_kernel(int* __restrict__ rowptr,
                                                    const int* __restrict__ bsum,
                                                    int* __restrict__ off)
{
    int t = threadIdx.x;
    int v = (t < (int)blockIdx.x) ? bsum[t] : 0;   // blockIdx.x <= 195
    __shared__ int sd[256];
    sd[t] = v;
    __syncthreads();
    #pragma unroll
    for (int ofs = 1; ofs < 256; ofs <<= 1) {
        int u = (t >= ofs) ? sd[t - ofs] : 0;
        __syncthreads();
        sd[t] += u;
        __syncthreads();
    }
    int boff = sd[255];
    int i = blockIdx.x * 256 + t;
    if (i < N_NODES) {
        int r = rowptr[i] + boff;
        rowptr[i] = r;
        off[i] = r;
    }
}

__global__ __launch_bounds__(256) void scatter_kernel(const int* __restrict__ ei,
                                                      int* __restrict__ off,
                                                      int* __restrict__ src_csr)
{
    int t = blockIdx.x * 256 + threadIdx.x;
    if (t >= ET) return;
    int s, d;
    if (t < N_EDGES) { s = ei[t]; d = ei[N_EDGES + t]; } else { s = d = t - N_EDGES; }
    int pos = atomicAdd(&off[d], 1);
    src_csr[pos] = s;
}

// ---------------- fused lin1 (128 rows/block) + hist ------------------------
// blocks 0..390: layer-1 linear (both sides), 128 rows each;
// blocks 391..:  edge histogram (depends only on convert's hist zeroing).
__global__ __launch_bounds__(256) void lin1_hist_kernel(
    const u16* __restrict__ X, const u16* __restrict__ Wt,   // Wt: [2][256][128]
    const u16* __restrict__ bl, const u16* __restrict__ br,
    u16* __restrict__ Yl, u16* __restrict__ Yr, int nrows,
    const int* __restrict__ ei, int* __restrict__ hist)
{
    constexpr int K = 128, N = 256, LS = K + 8;
    __shared__ __align__(16) u16 sX[128 * LS];
    __shared__ __align__(16) u16 sW[64 * LS];

    if (blockIdx.x >= LIN1_BLOCKS) {
        int t = (blockIdx.x - LIN1_BLOCKS) * 256 + threadIdx.x;
        if (t < ET) {
            int d = (t < N_EDGES) ? ei[N_EDGES + t] : t - N_EDGES;
            atomicAdd(&hist[d], 1);
        }
        return;
    }

    const bool f32m = detect_f32((const unsigned*)X);
    const float* X32 = (const float*)X;
    const int row0 = blockIdx.x * 128;
    const int wave = threadIdx.x >> 6, lane = threadIdx.x & 63;
    const int quad = lane >> 4, l16 = lane & 15;

    // stage X tile (128 x 128), converting f32->bf16 if needed
    for (int i = threadIdx.x * 8; i < 128 * K; i += 2048) {
        int r = i >> 7, c = i & 127;
        int gr = row0 + r;
        u16* dst = &sX[r * LS + c];
        if (f32m) {
            float4 v0 = make_float4(0.f, 0.f, 0.f, 0.f), v1 = v0;
            if (gr < nrows) {
                v0 = *(const float4*)&X32[(size_t)gr * K + c];
                v1 = *(const float4*)&X32[(size_t)gr * K + c + 4];
            }
            ushort4 p0, p1;
            p0.x = f2bf(v0.x); p0.y = f2bf(v0.y); p0.z = f2bf(v0.z); p0.w = f2bf(v0.w);
            p1.x = f2bf(v1.x); p1.y = f2bf(v1.y); p1.z = f2bf(v1.z); p1.w = f2bf(v1.w);
            *(ushort4*)dst = p0;
            *(ushort4*)(dst + 4) = p1;
        } else {
            uint4 v = {0u, 0u, 0u, 0u};
            if (gr < nrows) v = *(const uint4*)&X[(size_t)gr * K + c];
            *(uint4*)dst = v;
        }
    }
    __syncthreads();

    // preload A-fragments for both 64-row sets (reused across all 8 rounds)
    short8 a0[4], a1[4];
    #pragma unroll
    for (int kk = 0; kk < 4; ++kk) {
        a0[kk] = *(const short8*)&sX[(wave * 16 + l16) * LS + kk * 32 + quad * 8];
        a1[kk] = *(const short8*)&sX[(64 + wave * 16 + l16) * LS + kk * 32 + quad * 8];
    }

    for (int side = 0; side < 2; ++side) {
        const u16* wbase = Wt + side * (N * K);
        const u16* bias  = side ? br : bl;
        u16* Y = side ? Yr : Yl;
        for (int ch = 0; ch < 4; ++ch) {
            __syncthreads();
            for (int i = threadIdx.x * 8; i < 64 * K; i += 2048) {
                int n = i >> 7, c = i & 127;
                *(uint4*)&sW[n * LS + c] = *(const uint4*)&wbase[(size_t)(ch * 64 + n) * K + c];
            }
            __syncthreads();
            floatx4 p0 = {0.f, 0.f, 0.f, 0.f}, p1 = p0, p2 = p0, p3 = p0;
            floatx4 q0 = p0, q1 = p0, q2 = p0, q3 = p0;
            #pragma unroll
            for (int kk = 0; kk < 4; ++kk) {
                short8 b0 = *(const short8*)&sW[(l16) * LS + kk * 32 + quad * 8];
                short8 b1 = *(const short8*)&sW[(16 + l16) * LS + kk * 32 + quad * 8];
                short8 b2 = *(const short8*)&sW[(32 + l16) * LS + kk * 32 + quad * 8];
                short8 b3 = *(const short8*)&sW[(48 + l16) * LS + kk * 32 + quad * 8];
                p0 = __builtin_amdgcn_mfma_f32_16x16x32_bf16(a0[kk], b0, p0, 0, 0, 0);
                p1 = __builtin_amdgcn_mfma_f32_16x16x32_bf16(a0[kk], b1, p1, 0, 0, 0);
                p2 = __builtin_amdgcn_mfma_f32_16x16x32_bf16(a0[kk], b2, p2, 0, 0, 0);
                p3 = __builtin_amdgcn_mfma_f32_16x16x32_bf16(a0[kk], b3, p3, 0, 0, 0);
                q0 = __builtin_amdgcn_mfma_f32_16x16x32_bf16(a1[kk], b0, q0, 0, 0, 0);
                q1 = __builtin_amdgcn_mfma_f32_16x16x32_bf16(a1[kk], b1, q1, 0, 0, 0);
                q2 = __builtin_amdgcn_mfma_f32_16x16x32_bf16(a1[kk], b2, q2, 0, 0, 0);
                q3 = __builtin_amdgcn_mfma_f32_16x16x32_bf16(a1[kk], b3, q3, 0, 0, 0);
            }
            const int rb0 = row0 + wave * 16 + quad * 4;
            #pragma unroll
            for (int cf = 0; cf < 4; ++cf) {
                const floatx4 av = (cf == 0) ? p0 : (cf == 1) ? p1 : (cf == 2) ? p2 : p3;
                const floatx4 bw = (cf == 0) ? q0 : (cf == 1) ? q1 : (cf == 2) ? q2 : q3;
                const int col = ch * 64 + cf * 16 + l16;
                const float bv = bf2f(bias[col]);
                #pragma unroll
                for (int r = 0; r < 4; ++r) {
                    int rowA = rb0 + r;
                    if (rowA < nrows) Y[(size_t)rowA * N + col] = f2bf(av[r] + bv);
                    int rowB = rowA + 64;
                    if (rowB < nrows) Y[(size_t)rowB * N + col] = f2bf(bw[r] + bv);
                }
            }
        }
    }
}

// ---------------- fused layer-2 linear (R11 LDS-staged form) ----------------
__global__ __launch_bounds__(256) void lin2_fused_kernel(
    const u16* __restrict__ X, const u16* __restrict__ Wt,   // Wt: [2][64][256]
    const u16* __restrict__ bl, const u16* __restrict__ br,
    u16* __restrict__ Yl, u16* __restrict__ Yr, int nrows)
{
    constexpr int K = 256, N = 64, LS = K + 8;
    __shared__ __align__(16) u16 sX[64 * LS];
    __shared__ __align__(16) u16 sW[64 * LS];
    const int row0 = blockIdx.x * 64;
    const int wave = threadIdx.x >> 6, lane = threadIdx.x & 63;
    const int quad = lane >> 4, l16 = lane & 15;

    for (int i = threadIdx.x * 8; i < 64 * K; i += 2048) {
        int r = i >> 8, c = i & 255;
        int gr = row0 + r;
        uint4 v = {0u, 0u, 0u, 0u};
        if (gr < nrows) v = *(const uint4*)&X[(size_t)gr * K + c];
        *(uint4*)&sX[r * LS + c] = v;
    }
    __syncthreads();

    short8 a[8];
    #pragma unroll
    for (int kk = 0; kk < 8; ++kk)
        a[kk] = *(const short8*)&sX[(wave * 16 + l16) * LS + kk * 32 + quad * 8];

    for (int side = 0; side < 2; ++side) {
        const u16* wbase = Wt + side * (N * K);
        const u16* bias  = side ? br : bl;
        u16* Y = side ? Yr : Yl;
        __syncthreads();
        for (int i = threadIdx.x * 8; i < 64 * K; i += 2048) {
            int n = i >> 8, c = i & 255;
            *(uint4*)&sW[n * LS + c] = *(const uint4*)&wbase[(size_t)n * K + c];
        }
        __syncthreads();
        floatx4 acc0 = {0.f, 0.f, 0.f, 0.f}, acc1 = acc0, acc2 = acc0, acc3 = acc0;
        #pragma unroll
        for (int kk = 0; kk < 8; ++kk) {
            short8 b0 = *(const short8*)&sW[(l16) * LS + kk * 32 + quad * 8];
            short8 b1 = *(const short8*)&sW[(16 + l16) * LS + kk * 32 + quad * 8];
            short8 b2 = *(const short8*)&sW[(32 + l16) * LS + kk * 32 + quad * 8];
            short8 b3 = *(const short8*)&sW[(48 + l16) * LS + kk * 32 + quad * 8];
            acc0 = __builtin_amdgcn_mfma_f32_16x16x32_bf16(a[kk], b0, acc0, 0, 0, 0);
            acc1 = __builtin_amdgcn_mfma_f32_16x16x32_bf16(a[kk], b1, acc1, 0, 0, 0);
            acc2 = __builtin_amdgcn_mfma_f32_16x16x32_bf16(a[kk], b2, acc2, 0, 0, 0);
            acc3 = __builtin_amdgcn_mfma_f32_16x16x32_bf16(a[kk], b3, acc3, 0, 0, 0);
        }
        const int rbase = row0 + wave * 16 + quad * 4;
        #pragma unroll
        for (int cf = 0; cf < 4; ++cf) {
            const floatx4 av = (cf == 0) ? acc0 : (cf == 1) ? acc1 : (cf == 2) ? acc2 : acc3;
            const int col = cf * 16 + l16;
            const float bv = bf2f(bias[col]);
            #pragma unroll
            for (int r = 0; r < 4; ++r) {
                int row = rbase + r;
                if (row < nrows) Y[(size_t)row * N + col] = f2bf(av[r] + bv);
            }
        }
    }
}

// ---------------- layer 1 fused per-node GATv2 (4 heads x 64 ch) ------------
__global__ __launch_bounds__(256) void node1_kernel(
    const u16* __restrict__ xl, const u16* __restrict__ xr,
    const int* __restrict__ rowptr, const int* __restrict__ hist,
    const int* __restrict__ src_csr, const u16* __restrict__ att,
    const u16* __restrict__ bias, u16* __restrict__ hout)
{
    const int d = __builtin_amdgcn_readfirstlane(blockIdx.x * 4 + (threadIdx.x >> 6));
    if (d >= N_NODES) return;
    const int l = threadIdx.x & 63;
    const int start = rowptr[d];
    const int deg = hist[d];

    uint2 auv = *(const uint2*)&att[l * 4];
    const f32x2 atA = up2(auv.x), atB = up2(auv.y);
    uint2 ruv = *(const uint2*)&xr[(size_t)d * C1 + l * 4];
    const f32x2 rA = up2(ruv.x), rB = up2(ruv.y);

    float m = -1e30f, la = 0.f;
    f32x2 accA = {0.f, 0.f}, accB = {0.f, 0.f};
    for (int j = 0; j < deg; j += 4) {
        const bool v1 = j + 1 < deg, v2 = j + 2 < deg, v3 = j + 3 < deg;
        int s0 = src_csr[start + j];
        int s1 = v1 ? src_csr[start + j + 1] : s0;
        int s2 = v2 ? src_csr[start + j + 2] : s0;
        int s3 = v3 ? src_csr[start + j + 3] : s0;
        uint2 u0 = *(const uint2*)&xl[(size_t)s0 * C1 + l * 4];
        uint2 u1 = *(const uint2*)&xl[(size_t)s1 * C1 + l * 4];
        uint2 u2 = *(const uint2*)&xl[(size_t)s2 * C1 + l * 4];
        uint2 u3 = *(const uint2*)&xl[(size_t)s3 * C1 + l * 4];
        f32x2 x0A = up2(u0.x), x0B = up2(u0.y);
        f32x2 x1A = up2(u1.x), x1B = up2(u1.y);
        f32x2 x2A = up2(u2.x), x2B = up2(u2.y);
        f32x2 x3A = up2(u3.x), x3B = up2(u3.y);
        f32x2 t, pv;
        t = x0A + rA; t = __builtin_elementwise_max(t, t * SLOPE); pv  = t * atA;
        t = x0B + rB; t = __builtin_elementwise_max(t, t * SLOPE); pv += t * atB;
        float p0 = pv.x + pv.y;
        t = x1A + rA; t = __builtin_elementwise_max(t, t * SLOPE); pv  = t * atA;
        t = x1B + rB; t = __builtin_elementwise_max(t, t * SLOPE); pv += t * atB;
        float p1 = pv.x + pv.y;
        t = x2A + rA; t = __builtin_elementwise_max(t, t * SLOPE); pv  = t * atA;
        t = x2B + rB; t = __builtin_elementwise_max(t, t * SLOPE); pv += t * atB;
        float p2 = pv.x + pv.y;
        t = x3A + rA; t = __builtin_elementwise_max(t, t * SLOPE); pv  = t * atA;
        t = x3B + rB; t = __builtin_elementwise_max(t, t * SLOPE); pv += t * atB;
        float p3 = pv.x + pv.y;
        p0 = red16(p0); p1 = red16(p1); p2 = red16(p2); p3 = red16(p3);
        float pm = p0;
        if (v1) pm = fmaxf(pm, p1);
        if (v2) pm = fmaxf(pm, p2);
        if (v3) pm = fmaxf(pm, p3);
        float mn = fmaxf(m, pm);
        float sc = __expf(m - mn);
        float w0 = __expf(p0 - mn);
        float w1 = v1 ? __expf(p1 - mn) : 0.f;
        float w2 = v2 ? __expf(p2 - mn) : 0.f;
        float w3 = v3 ? __expf(p3 - mn) : 0.f;
        la = la * sc + w0 + w1 + w2 + w3;
        accA = accA * sc + x0A * w0 + x1A * w1 + x2A * w2 + x3A * w3;
        accB = accB * sc + x0B * w0 + x1B * w1 + x2B * w2 + x3B * w3;
        m = mn;
    }
    const float inv = 1.f / la;
    const int c = l * 4;
    float v0 = accA.x * inv + bf2f(bias[c + 0]);
    float v1 = accA.y * inv + bf2f(bias[c + 1]);
    float v2 = accB.x * inv + bf2f(bias[c + 2]);
    float v3 = accB.y * inv + bf2f(bias[c + 3]);
    v0 = v0 > 0.f ? v0 : __expf(fminf(v0, 0.f)) - 1.f;
    v1 = v1 > 0.f ? v1 : __expf(fminf(v1, 0.f)) - 1.f;
    v2 = v2 > 0.f ? v2 : __expf(fminf(v2, 0.f)) - 1.f;
    v3 = v3 > 0.f ? v3 : __expf(fminf(v3, 0.f)) - 1.f;
    ushort4 o;
    o.x = f2bf(v0); o.y = f2bf(v1); o.z = f2bf(v2); o.w = f2bf(v3);
    *(ushort4*)&hout[(size_t)d * C1 + c] = o;
}

// ---------------- layer 2 fused per-node GATv2 (1 head x 64 ch) --------------
__global__ __launch_bounds__(256) void node2_kernel(
    const u16* __restrict__ xl, const u16* __restrict__ xr,
    const int* __restrict__ rowptr, const int* __restrict__ hist,
    const int* __restrict__ src_csr, const u16* __restrict__ att,
    const u16* __restrict__ bias, void* __restrict__ outp,
    const unsigned* __restrict__ xorig)
{
    const bool f32o = detect_f32(xorig);
    const int d = __builtin_amdgcn_readfirstlane(blockIdx.x * 4 + (threadIdx.x >> 6));
    if (d >= N_NODES) return;
    const int l = threadIdx.x & 63;
    const int start = rowptr[d];
    const int deg = hist[d];
    const int g = l >> 4, sub = l & 15;
    const int c0 = sub * 4;

    uint2 auv = *(const uint2*)&att[c0];
    const f32x2 atA = up2(auv.x), atB = up2(auv.y);
    uint2 ruv = *(const uint2*)&xr[(size_t)d * OUTC + c0];
    const f32x2 rA = up2(ruv.x), rB = up2(ruv.y);

    float m = -1e30f, la = 0.f;
    f32x2 accA = {0.f, 0.f}, accB = {0.f, 0.f};
    for (int j = 0; j < deg; j += 4) {
        const bool valid = j + g < deg;
        int s = valid ? src_csr[start + j + g] : d;
        uint2 uv = *(const uint2*)&xl[(size_t)s * OUTC + c0];
        f32x2 xA = up2(uv.x), xB = up2(uv.y);
        f32x2 t, pv;
        t = xA + rA; t = __builtin_elementwise_max(t, t * SLOPE); pv  = t * atA;
        t = xB + rB; t = __builtin_elementwise_max(t, t * SLOPE); pv += t * atB;
        float p = pv.x + pv.y;
        p = red16(p);
        float pvv = valid ? p : -1e30f;
        float mn = fmaxf(m, pvv);
        float sc = __expf(m - mn);
        float w  = valid ? __expf(p - mn) : 0.f;
        la = la * sc + w;
        accA = accA * sc + xA * w;
        accB = accB * sc + xB * w;
        m = mn;
    }
    #pragma unroll
    for (int ofs = 16; ofs <= 32; ofs <<= 1) {
        float mo = __shfl_xor(m, ofs);
        float lo = __shfl_xor(la, ofs);
        float bax = __shfl_xor(accA.x, ofs);
        float bay = __shfl_xor(accA.y, ofs);
        float bbx = __shfl_xor(accB.x, ofs);
        float bby = __shfl_xor(accB.y, ofs);
        float mn = fmaxf(m, mo);
        float s0 = __expf(m - mn), s1 = __expf(mo - mn);
        la = la * s0 + lo * s1;
        accA.x = accA.x * s0 + bax * s1;
        accA.y = accA.y * s0 + bay * s1;
        accB.x = accB.x * s0 + bbx * s1;
        accB.y = accB.y * s0 + bby * s1;
        m = mn;
    }
    if (g == 0) {
        const float inv = 1.f / la;
        float v0 = accA.x * inv + bf2f(bias[c0 + 0]);
        float v1 = accA.y * inv + bf2f(bias[c0 + 1]);
        float v2 = accB.x * inv + bf2f(bias[c0 + 2]);
        float v3 = accB.y * inv + bf2f(bias[c0 + 3]);
        if (f32o) {
            float4 o = make_float4(v0, v1, v2, v3);
            *(float4*)&((float*)outp)[(size_t)d * OUTC + c0] = o;
        } else {
            ushort4 o;
            o.x = f2bf(v0); o.y = f2bf(v1); o.z = f2bf(v2); o.w = f2bf(v3);
            *(ushort4*)&((u16*)outp)[(size_t)d * OUTC + c0] = o;
        }
    }
}

extern "C" void kernel_launch(void* const* d_in, const int* in_sizes, int n_in,
                              void* d_out, int out_size, void* d_ws, size_t ws_size,
                              hipStream_t stream)
{
    const void* x  = d_in[0];
    const int*  ei = (const int*)d_in[1];

    char* ws = (char*)d_ws;
    u16* xl1     = (u16*)(ws + 0);          // 25.6 MB
    u16* xr1     = (u16*)(ws + 25600000);   // 25.6 MB
    u16* hbuf    = (u16*)(ws + 51200000);   // 25.6 MB
    u16* xl2     = (u16*)(ws + 0);          // overlay xl1 (dead after node1)
    u16* xr2     = (u16*)(ws + 6400000);
    int* hist    = (int*)(ws + 76800000);
    int* rowptr  = (int*)(ws + 77000000);
    int* off     = (int*)(ws + 77200000);
    int* src_csr = (int*)(ws + 77400000);   // 1.8 MB
    u16* prm     = (u16*)(ws + 79200064);   // 1280 u16 small params
    u16* wt      = (u16*)(ws + 79210240);   // 98304 u16 transposed weights
    int* bsum    = (int*)(ws + 79410000);

    u16* bl1   = prm + 0;
    u16* br1   = prm + 256;
    u16* att1  = prm + 512;
    u16* bias1 = prm + 768;
    u16* bl2   = prm + 1024;
    u16* br2   = prm + 1088;
    u16* att2  = prm + 1152;
    u16* bias2 = prm + 1216;
    u16* wt1   = wt + 0;       // [2][256][128]
    u16* wt2   = wt + 65536;   // [2][64][256]

    // D1: param convert + hist zero
    convert_all_kernel<<<581, 256, 0, stream>>>(
        (const unsigned*)x,
        d_in[2], d_in[4], d_in[8], d_in[10],
        d_in[3], d_in[5], d_in[6], d_in[7], d_in[9], d_in[11], d_in[12], d_in[13],
        wt, prm, hist);

    // D2: lin1 (128 rows/block) + hist fused (both depend only on D1)
    const int eb = (ET + 255) / 256;   // 1758 hist blocks
    lin1_hist_kernel<<<LIN1_BLOCKS + eb, 256, 0, stream>>>(
        (const u16*)x, wt1, bl1, br1, xl1, xr1, N_NODES, ei, hist);

    // D3-D5: CSR scan + scatter
    scan1_kernel<<<196, 256, 0, stream>>>(hist, rowptr, bsum);
    scan3_kernel<<<196, 256, 0, stream>>>(rowptr, bsum, off);
    scatter_kernel<<<eb, 256, 0, stream>>>(ei, off, src_csr);

    // D6-D8: node1, lin2, node2
    const int nb = (N_NODES * 64 + 255) / 256;   // 12500 blocks
    node1_kernel<<<nb, 256, 0, stream>>>(xl1, xr1, rowptr, hist, src_csr, att1, bias1, hbuf);
    lin2_fused_kernel<<<(N_NODES + 63) / 64, 256, 0, stream>>>(hbuf, wt2, bl2, br2, xl2, xr2, N_NODES);
    node2_kernel<<<nb, 256, 0, stream>>>(xl2, xr2, rowptr, hist, src_csr, att2, bias2, d_out,
                                         (const unsigned*)x);
}

// Round 15
// 245.619 us; speedup vs baseline: 1.2918x; 1.0246x over previous
//
#include <hip/hip_runtime.h>
#include <hip/hip_bf16.h>

typedef unsigned short u16;
typedef __attribute__((ext_vector_type(8))) short short8;
typedef __attribute__((ext_vector_type(4))) float floatx4;
typedef __attribute__((ext_vector_type(2))) float f32x2;

#define N_NODES 50000
#define N_EDGES 400000
#define ET      450000   // edges + self loops
#define F_IN    128
#define C1      256      // H*HID
#define HID     64
#define OUTC    64
#define SLOPE   0.2f
#define LIN1_BLOCKS 782  // ceil(50000/64)

__device__ __forceinline__ float bf2f(u16 v) {
    return __uint_as_float(((unsigned)v) << 16);
}
__device__ __forceinline__ float bflo(unsigned u) { return __uint_as_float(u << 16); }
__device__ __forceinline__ float bfhi(unsigned u) { return __uint_as_float(u & 0xffff0000u); }
__device__ __forceinline__ u16 f2bf(float f) {   // round-to-nearest-even
    unsigned u = __float_as_uint(f);
    return (u16)((u + 0x7fffu + ((u >> 16) & 1u)) >> 16);
}
__device__ __forceinline__ f32x2 up2(unsigned u) {
    f32x2 r; r.x = bflo(u); r.y = bfhi(u); return r;
}
template<int CTRL>
__device__ __forceinline__ float dpp_add(float x) {
    return x + __int_as_float(__builtin_amdgcn_update_dpp(
        0, __float_as_int(x), CTRL, 0xF, 0xF, true));
}
__device__ __forceinline__ float red16(float p) {
    p = dpp_add<0xB1>(p);
    p = dpp_add<0x4E>(p);
    p = dpp_add<0x141>(p);
    p = dpp_add<0x140>(p);
    return p;
}
__device__ __forceinline__ bool detect_f32(const unsigned* __restrict__ xw) {
    unsigned w = xw[threadIdx.x & 63];
    unsigned aexp = (w >> 7) & 0xFFu;
    unsigned long long b = __ballot(aexp >= 170u || aexp <= 40u);
    return __popcll(b) >= 16;
}

// ---------------- fused param convert + hist zero ---------------------------
__global__ __launch_bounds__(256) void convert_all_kernel(
    const unsigned* __restrict__ xw,
    const void* wl1, const void* wr1, const void* wl2, const void* wr2,
    const void* s0, const void* s1, const void* s2, const void* s3,
    const void* s4, const void* s5, const void* s6, const void* s7,
    u16* __restrict__ wt, u16* __restrict__ prm, int* __restrict__ hist)
{
    if (blockIdx.x >= 385) {
        int idx = (blockIdx.x - 385) * 256 + threadIdx.x;
        if (idx < N_NODES) hist[idx] = 0;
        return;
    }
    bool f32m = detect_f32(xw);
    if (blockIdx.x == 384) {
        for (int t = threadIdx.x; t < 1280; t += 256) {
            const void* src; int local;
            if      (t < 256)  { src = s0; local = t; }
            else if (t < 512)  { src = s1; local = t - 256; }
            else if (t < 768)  { src = s2; local = t - 512; }
            else if (t < 1024) { src = s3; local = t - 768; }
            else if (t < 1088) { src = s4; local = t - 1024; }
            else if (t < 1152) { src = s5; local = t - 1088; }
            else if (t < 1216) { src = s6; local = t - 1152; }
            else               { src = s7; local = t - 1216; }
            prm[t] = f32m ? f2bf(((const float*)src)[local]) : ((const u16*)src)[local];
        }
        return;
    }
    int t = blockIdx.x * 256 + threadIdx.x;   // 98304 total
    const void* src; int local, k, n, K, base;
    if (t < 32768)      { src = wl1; local = t;         k = local >> 8; n = local & 255; K = 128; base = 0; }
    else if (t < 65536) { src = wr1; local = t - 32768; k = local >> 8; n = local & 255; K = 128; base = 32768; }
    else if (t < 81920) { src = wl2; local = t - 65536; k = local >> 6; n = local & 63;  K = 256; base = 65536; }
    else                { src = wr2; local = t - 81920; k = local >> 6; n = local & 63;  K = 256; base = 81920; }
    u16 v = f32m ? f2bf(((const float*)src)[local]) : ((const u16*)src)[local];
    wt[base + n * K + k] = v;
}

// ---------------- CSR scan (phases) ----------------
__global__ __launch_bounds__(256) void scan1_kernel(const int* __restrict__ hist,
                                                    int* __restrict__ rowptr,
                                                    int* __restrict__ bsum)
{
    int t = threadIdx.x;
    int i = blockIdx.x * 256 + t;
    int v = (i < N_NODES) ? hist[i] : 0;
    __shared__ int sd[256];
    sd[t] = v;
    __syncthreads();
    #pragma unroll
    for (int ofs = 1; ofs < 256; ofs <<= 1) {
        int u = (t >= ofs) ? sd[t - ofs] : 0;
        __syncthreads();
        sd[t] += u;
        __syncthreads();
    }
    if (i < N_NODES) rowptr[i] = sd[t] - v;
    if (t == 255) bsum[blockIdx.x] = sd[255];
}

__global__ __launch_bounds__(256) void scan3_kernel(int* __restrict__ rowptr,
                                                    const int* __restrict__ bsum,
                                                    int* __restrict__ off)
{
    int t = threadIdx.x;
    int v = (t < (int)blockIdx.x) ? bsum[t] : 0;   // blockIdx.x <= 195
    __shared__ int sd[256];
    sd[t] = v;
    __syncthreads();
    #pragma unroll
    for (int ofs = 1; ofs < 256; ofs <<= 1) {
        int u = (t >= ofs) ? sd[t - ofs] : 0;
        __syncthreads();
        sd[t] += u;
        __syncthreads();
    }
    int boff = sd[255];
    int i = blockIdx.x * 256 + t;
    if (i < N_NODES) {
        int r = rowptr[i] + boff;
        rowptr[i] = r;
        off[i] = r;
    }
}

__global__ __launch_bounds__(256) void scatter_kernel(const int* __restrict__ ei,
                                                      int* __restrict__ off,
                                                      int* __restrict__ src_csr)
{
    int t = blockIdx.x * 256 + threadIdx.x;
    if (t >= ET) return;
    int s, d;
    if (t < N_EDGES) { s = ei[t]; d = ei[N_EDGES + t]; } else { s = d = t - N_EDGES; }
    int pos = atomicAdd(&off[d], 1);
    src_csr[pos] = s;
}

// ---------------- fused lin1 (64 rows/block) + hist -------------------------
// blocks 0..781: layer-1 linear (both sides), 64 rows each;
// blocks 782.. : edge histogram (depends only on convert's hist zeroing).
__global__ __launch_bounds__(256) void lin1_hist_kernel(
    const u16* __restrict__ X, const u16* __restrict__ Wt,   // Wt: [2][256][128]
    const u16* __restrict__ bl, const u16* __restrict__ br,
    u16* __restrict__ Yl, u16* __restrict__ Yr, int nrows,
    const int* __restrict__ ei, int* __restrict__ hist)
{
    constexpr int K = 128, N = 256, LS = K + 8;
    __shared__ __align__(16) u16 sX[64 * LS];
    __shared__ __align__(16) u16 sW[64 * LS];

    if (blockIdx.x >= LIN1_BLOCKS) {
        int t = (blockIdx.x - LIN1_BLOCKS) * 256 + threadIdx.x;
        if (t < ET) {
            int d = (t < N_EDGES) ? ei[N_EDGES + t] : t - N_EDGES;
            atomicAdd(&hist[d], 1);
        }
        return;
    }

    const bool f32m = detect_f32((const unsigned*)X);
    const float* X32 = (const float*)X;
    const int row0 = blockIdx.x * 64;
    const int wave = threadIdx.x >> 6, lane = threadIdx.x & 63;
    const int quad = lane >> 4, l16 = lane & 15;

    for (int i = threadIdx.x * 8; i < 64 * K; i += 2048) {
        int r = i >> 7, c = i & 127;
        int gr = row0 + r;
        u16* dst = &sX[r * LS + c];
        if (f32m) {
            float4 v0 = make_float4(0.f, 0.f, 0.f, 0.f), v1 = v0;
            if (gr < nrows) {
                v0 = *(const float4*)&X32[(size_t)gr * K + c];
                v1 = *(const float4*)&X32[(size_t)gr * K + c + 4];
            }
            ushort4 p0, p1;
            p0.x = f2bf(v0.x); p0.y = f2bf(v0.y); p0.z = f2bf(v0.z); p0.w = f2bf(v0.w);
            p1.x = f2bf(v1.x); p1.y = f2bf(v1.y); p1.z = f2bf(v1.z); p1.w = f2bf(v1.w);
            *(ushort4*)dst = p0;
            *(ushort4*)(dst + 4) = p1;
        } else {
            uint4 v = {0u, 0u, 0u, 0u};
            if (gr < nrows) v = *(const uint4*)&X[(size_t)gr * K + c];
            *(uint4*)dst = v;
        }
    }
    __syncthreads();

    // preload A-fragments once (reused across all 8 col rounds)
    short8 a[4];
    #pragma unroll
    for (int kk = 0; kk < 4; ++kk)
        a[kk] = *(const short8*)&sX[(wave * 16 + l16) * LS + kk * 32 + quad * 8];

    for (int side = 0; side < 2; ++side) {
        const u16* wbase = Wt + side * (N * K);
        const u16* bias  = side ? br : bl;
        u16* Y = side ? Yr : Yl;
        for (int ch = 0; ch < 4; ++ch) {
            __syncthreads();
            for (int i = threadIdx.x * 8; i < 64 * K; i += 2048) {
                int n = i >> 7, c = i & 127;
                *(uint4*)&sW[n * LS + c] = *(const uint4*)&wbase[(size_t)(ch * 64 + n) * K + c];
            }
            __syncthreads();
            floatx4 acc0 = {0.f, 0.f, 0.f, 0.f}, acc1 = acc0, acc2 = acc0, acc3 = acc0;
            #pragma unroll
            for (int kk = 0; kk < 4; ++kk) {
                short8 b0 = *(const short8*)&sW[(l16) * LS + kk * 32 + quad * 8];
                short8 b1 = *(const short8*)&sW[(16 + l16) * LS + kk * 32 + quad * 8];
                short8 b2 = *(const short8*)&sW[(32 + l16) * LS + kk * 32 + quad * 8];
                short8 b3 = *(const short8*)&sW[(48 + l16) * LS + kk * 32 + quad * 8];
                acc0 = __builtin_amdgcn_mfma_f32_16x16x32_bf16(a[kk], b0, acc0, 0, 0, 0);
                acc1 = __builtin_amdgcn_mfma_f32_16x16x32_bf16(a[kk], b1, acc1, 0, 0, 0);
                acc2 = __builtin_amdgcn_mfma_f32_16x16x32_bf16(a[kk], b2, acc2, 0, 0, 0);
                acc3 = __builtin_amdgcn_mfma_f32_16x16x32_bf16(a[kk], b3, acc3, 0, 0, 0);
            }
            const int rbase = row0 + wave * 16 + quad * 4;
            #pragma unroll
            for (int cf = 0; cf < 4; ++cf) {
                const floatx4 av = (cf == 0) ? acc0 : (cf == 1) ? acc1 : (cf == 2) ? acc2 : acc3;
                const int col = ch * 64 + cf * 16 + l16;
                const float bv = bf2f(bias[col]);
                #pragma unroll
                for (int r = 0; r < 4; ++r) {
                    int row = rbase + r;
                    if (row < nrows) Y[(size_t)row * N + col] = f2bf(av[r] + bv);
                }
            }
        }
    }
}

// ---------------- fused layer-2 linear (R11 LDS-staged form) ----------------
__global__ __launch_bounds__(256) void lin2_fused_kernel(
    const u16* __restrict__ X, const u16* __restrict__ Wt,   // Wt: [2][64][256]
    const u16* __restrict__ bl, const u16* __restrict__ br,
    u16* __restrict__ Yl, u16* __restrict__ Yr, int nrows)
{
    constexpr int K = 256, N = 64, LS = K + 8;
    __shared__ __align__(16) u16 sX[64 * LS];
    __shared__ __align__(16) u16 sW[64 * LS];
    const int row0 = blockIdx.x * 64;
    const int wave = threadIdx.x >> 6, lane = threadIdx.x & 63;
    const int quad = lane >> 4, l16 = lane & 15;

    for (int i = threadIdx.x * 8; i < 64 * K; i += 2048) {
        int r = i >> 8, c = i & 255;
        int gr = row0 + r;
        uint4 v = {0u, 0u, 0u, 0u};
        if (gr < nrows) v = *(const uint4*)&X[(size_t)gr * K + c];
        *(uint4*)&sX[r * LS + c] = v;
    }
    __syncthreads();

    short8 a[8];
    #pragma unroll
    for (int kk = 0; kk < 8; ++kk)
        a[kk] = *(const short8*)&sX[(wave * 16 + l16) * LS + kk * 32 + quad * 8];

    for (int side = 0; side < 2; ++side) {
        const u16* wbase = Wt + side * (N * K);
        const u16* bias  = side ? br : bl;
        u16* Y = side ? Yr : Yl;
        __syncthreads();
        for (int i = threadIdx.x * 8; i < 64 * K; i += 2048) {
            int n = i >> 8, c = i & 255;
            *(uint4*)&sW[n * LS + c] = *(const uint4*)&wbase[(size_t)n * K + c];
        }
        __syncthreads();
        floatx4 acc0 = {0.f, 0.f, 0.f, 0.f}, acc1 = acc0, acc2 = acc0, acc3 = acc0;
        #pragma unroll
        for (int kk = 0; kk < 8; ++kk) {
            short8 b0 = *(const short8*)&sW[(l16) * LS + kk * 32 + quad * 8];
            short8 b1 = *(const short8*)&sW[(16 + l16) * LS + kk * 32 + quad * 8];
            short8 b2 = *(const short8*)&sW[(32 + l16) * LS + kk * 32 + quad * 8];
            short8 b3 = *(const short8*)&sW[(48 + l16) * LS + kk * 32 + quad * 8];
            acc0 = __builtin_amdgcn_mfma_f32_16x16x32_bf16(a[kk], b0, acc0, 0, 0, 0);
            acc1 = __builtin_amdgcn_mfma_f32_16x16x32_bf16(a[kk], b1, acc1, 0, 0, 0);
            acc2 = __builtin_amdgcn_mfma_f32_16x16x32_bf16(a[kk], b2, acc2, 0, 0, 0);
            acc3 = __builtin_amdgcn_mfma_f32_16x16x32_bf16(a[kk], b3, acc3, 0, 0, 0);
        }
        const int rbase = row0 + wave * 16 + quad * 4;
        #pragma unroll
        for (int cf = 0; cf < 4; ++cf) {
            const floatx4 av = (cf == 0) ? acc0 : (cf == 1) ? acc1 : (cf == 2) ? acc2 : acc3;
            const int col = cf * 16 + l16;
            const float bv = bf2f(bias[col]);
            #pragma unroll
            for (int r = 0; r < 4; ++r) {
                int row = rbase + r;
                if (row < nrows) Y[(size_t)row * N + col] = f2bf(av[r] + bv);
            }
        }
    }
}

// ---------------- layer 1 fused per-node GATv2 (4 heads x 64 ch) ------------
__global__ __launch_bounds__(256) void node1_kernel(
    const u16* __restrict__ xl, const u16* __restrict__ xr,
    const int* __restrict__ rowptr, const int* __restrict__ hist,
    const int* __restrict__ src_csr, const u16* __restrict__ att,
    const u16* __restrict__ bias, u16* __restrict__ hout)
{
    const int d = __builtin_amdgcn_readfirstlane(blockIdx.x * 4 + (threadIdx.x >> 6));
    if (d >= N_NODES) return;
    const int l = threadIdx.x & 63;
    const int start = rowptr[d];
    const int deg = hist[d];

    uint2 auv = *(const uint2*)&att[l * 4];
    const f32x2 atA = up2(auv.x), atB = up2(auv.y);
    uint2 ruv = *(const uint2*)&xr[(size_t)d * C1 + l * 4];
    const f32x2 rA = up2(ruv.x), rB = up2(ruv.y);

    float m = -1e30f, la = 0.f;
    f32x2 accA = {0.f, 0.f}, accB = {0.f, 0.f};
    for (int j = 0; j < deg; j += 4) {
        const bool v1 = j + 1 < deg, v2 = j + 2 < deg, v3 = j + 3 < deg;
        int s0 = src_csr[start + j];
        int s1 = v1 ? src_csr[start + j + 1] : s0;
        int s2 = v2 ? src_csr[start + j + 2] : s0;
        int s3 = v3 ? src_csr[start + j + 3] : s0;
        uint2 u0 = *(const uint2*)&xl[(size_t)s0 * C1 + l * 4];
        uint2 u1 = *(const uint2*)&xl[(size_t)s1 * C1 + l * 4];
        uint2 u2 = *(const uint2*)&xl[(size_t)s2 * C1 + l * 4];
        uint2 u3 = *(const uint2*)&xl[(size_t)s3 * C1 + l * 4];
        f32x2 x0A = up2(u0.x), x0B = up2(u0.y);
        f32x2 x1A = up2(u1.x), x1B = up2(u1.y);
        f32x2 x2A = up2(u2.x), x2B = up2(u2.y);
        f32x2 x3A = up2(u3.x), x3B = up2(u3.y);
        f32x2 t, pv;
        t = x0A + rA; t = __builtin_elementwise_max(t, t * SLOPE); pv  = t * atA;
        t = x0B + rB; t = __builtin_elementwise_max(t, t * SLOPE); pv += t * atB;
        float p0 = pv.x + pv.y;
        t = x1A + rA; t = __builtin_elementwise_max(t, t * SLOPE); pv  = t * atA;
        t = x1B + rB; t = __builtin_elementwise_max(t, t * SLOPE); pv += t * atB;
        float p1 = pv.x + pv.y;
        t = x2A + rA; t = __builtin_elementwise_max(t, t * SLOPE); pv  = t * atA;
        t = x2B + rB; t = __builtin_elementwise_max(t, t * SLOPE); pv += t * atB;
        float p2 = pv.x + pv.y;
        t = x3A + rA; t = __builtin_elementwise_max(t, t * SLOPE); pv  = t * atA;
        t = x3B + rB; t = __builtin_elementwise_max(t, t * SLOPE); pv += t * atB;
        float p3 = pv.x + pv.y;
        p0 = red16(p0); p1 = red16(p1); p2 = red16(p2); p3 = red16(p3);
        float pm = p0;
        if (v1) pm = fmaxf(pm, p1);
        if (v2) pm = fmaxf(pm, p2);
        if (v3) pm = fmaxf(pm, p3);
        float mn = fmaxf(m, pm);
        float sc = __expf(m - mn);
        float w0 = __expf(p0 - mn);
        float w1 = v1 ? __expf(p1 - mn) : 0.f;
        float w2 = v2 ? __expf(p2 - mn) : 0.f;
        float w3 = v3 ? __expf(p3 - mn) : 0.f;
        la = la * sc + w0 + w1 + w2 + w3;
        accA = accA * sc + x0A * w0 + x1A * w1 + x2A * w2 + x3A * w3;
        accB = accB * sc + x0B * w0 + x1B * w1 + x2B * w2 + x3B * w3;
        m = mn;
    }
    const float inv = 1.f / la;
    const int c = l * 4;
    float v0 = accA.x * inv + bf2f(bias[c + 0]);
    float v1 = accA.y * inv + bf2f(bias[c + 1]);
    float v2 = accB.x * inv + bf2f(bias[c + 2]);
    float v3 = accB.y * inv + bf2f(bias[c + 3]);
    v0 = v0 > 0.f ? v0 : __expf(fminf(v0, 0.f)) - 1.f;
    v1 = v1 > 0.f ? v1 : __expf(fminf(v1, 0.f)) - 1.f;
    v2 = v2 > 0.f ? v2 : __expf(fminf(v2, 0.f)) - 1.f;
    v3 = v3 > 0.f ? v3 : __expf(fminf(v3, 0.f)) - 1.f;
    ushort4 o;
    o.x = f2bf(v0); o.y = f2bf(v1); o.z = f2bf(v2); o.w = f2bf(v3);
    *(ushort4*)&hout[(size_t)d * C1 + c] = o;
}

// ---------------- layer 2 fused per-node GATv2 (1 head x 64 ch) --------------
__global__ __launch_bounds__(256) void node2_kernel(
    const u16* __restrict__ xl, const u16* __restrict__ xr,
    const int* __restrict__ rowptr, const int* __restrict__ hist,
    const int* __restrict__ src_csr, const u16* __restrict__ att,
    const u16* __restrict__ bias, void* __restrict__ outp,
    const unsigned* __restrict__ xorig)
{
    const bool f32o = detect_f32(xorig);
    const int d = __builtin_amdgcn_readfirstlane(blockIdx.x * 4 + (threadIdx.x >> 6));
    if (d >= N_NODES) return;
    const int l = threadIdx.x & 63;
    const int start = rowptr[d];
    const int deg = hist[d];
    const int g = l >> 4, sub = l & 15;
    const int c0 = sub * 4;

    uint2 auv = *(const uint2*)&att[c0];
    const f32x2 atA = up2(auv.x), atB = up2(auv.y);
    uint2 ruv = *(const uint2*)&xr[(size_t)d * OUTC + c0];
    const f32x2 rA = up2(ruv.x), rB = up2(ruv.y);

    float m = -1e30f, la = 0.f;
    f32x2 accA = {0.f, 0.f}, accB = {0.f, 0.f};
    for (int j = 0; j < deg; j += 4) {
        const bool valid = j + g < deg;
        int s = valid ? src_csr[start + j + g] : d;
        uint2 uv = *(const uint2*)&xl[(size_t)s * OUTC + c0];
        f32x2 xA = up2(uv.x), xB = up2(uv.y);
        f32x2 t, pv;
        t = xA + rA; t = __builtin_elementwise_max(t, t * SLOPE); pv  = t * atA;
        t = xB + rB; t = __builtin_elementwise_max(t, t * SLOPE); pv += t * atB;
        float p = pv.x + pv.y;
        p = red16(p);
        float pvv = valid ? p : -1e30f;
        float mn = fmaxf(m, pvv);
        float sc = __expf(m - mn);
        float w  = valid ? __expf(p - mn) : 0.f;
        la = la * sc + w;
        accA = accA * sc + xA * w;
        accB = accB * sc + xB * w;
        m = mn;
    }
    #pragma unroll
    for (int ofs = 16; ofs <= 32; ofs <<= 1) {
        float mo = __shfl_xor(m, ofs);
        float lo = __shfl_xor(la, ofs);
        float bax = __shfl_xor(accA.x, ofs);
        float bay = __shfl_xor(accA.y, ofs);
        float bbx = __shfl_xor(accB.x, ofs);
        float bby = __shfl_xor(accB.y, ofs);
        float mn = fmaxf(m, mo);
        float s0 = __expf(m - mn), s1 = __expf(mo - mn);
        la = la * s0 + lo * s1;
        accA.x = accA.x * s0 + bax * s1;
        accA.y = accA.y * s0 + bay * s1;
        accB.x = accB.x * s0 + bbx * s1;
        accB.y = accB.y * s0 + bby * s1;
        m = mn;
    }
    if (g == 0) {
        const float inv = 1.f / la;
        float v0 = accA.x * inv + bf2f(bias[c0 + 0]);
        float v1 = accA.y * inv + bf2f(bias[c0 + 1]);
        float v2 = accB.x * inv + bf2f(bias[c0 + 2]);
        float v3 = accB.y * inv + bf2f(bias[c0 + 3]);
        if (f32o) {
            float4 o = make_float4(v0, v1, v2, v3);
            *(float4*)&((float*)outp)[(size_t)d * OUTC + c0] = o;
        } else {
            ushort4 o;
            o.x = f2bf(v0); o.y = f2bf(v1); o.z = f2bf(v2); o.w = f2bf(v3);
            *(ushort4*)&((u16*)outp)[(size_t)d * OUTC + c0] = o;
        }
    }
}

extern "C" void kernel_launch(void* const* d_in, const int* in_sizes, int n_in,
                              void* d_out, int out_size, void* d_ws, size_t ws_size,
                              hipStream_t stream)
{
    const void* x  = d_in[0];
    const int*  ei = (const int*)d_in[1];

    char* ws = (char*)d_ws;
    u16* xl1     = (u16*)(ws + 0);          // 25.6 MB
    u16* xr1     = (u16*)(ws + 25600000);   // 25.6 MB
    u16* hbuf    = (u16*)(ws + 51200000);   // 25.6 MB
    u16* xl2     = (u16*)(ws + 0);          // overlay xl1 (dead after node1)
    u16* xr2     = (u16*)(ws + 6400000);
    int* hist    = (int*)(ws + 76800000);
    int* rowptr  = (int*)(ws + 77000000);
    int* off     = (int*)(ws + 77200000);
    int* src_csr = (int*)(ws + 77400000);   // 1.8 MB
    u16* prm     = (u16*)(ws + 79200064);   // 1280 u16 small params
    u16* wt      = (u16*)(ws + 79210240);   // 98304 u16 transposed weights
    int* bsum    = (int*)(ws + 79410000);

    u16* bl1   = prm + 0;
    u16* br1   = prm + 256;
    u16* att1  = prm + 512;
    u16* bias1 = prm + 768;
    u16* bl2   = prm + 1024;
    u16* br2   = prm + 1088;
    u16* att2  = prm + 1152;
    u16* bias2 = prm + 1216;
    u16* wt1   = wt + 0;       // [2][256][128]
    u16* wt2   = wt + 65536;   // [2][64][256]

    // D1: param convert + hist zero
    convert_all_kernel<<<581, 256, 0, stream>>>(
        (const unsigned*)x,
        d_in[2], d_in[4], d_in[8], d_in[10],
        d_in[3], d_in[5], d_in[6], d_in[7], d_in[9], d_in[11], d_in[12], d_in[13],
        wt, prm, hist);

    // D2: lin1 (64 rows/block) + hist fused
    const int eb = (ET + 255) / 256;   // 1758 hist blocks
    lin1_hist_kernel<<<LIN1_BLOCKS + eb, 256, 0, stream>>>(
        (const u16*)x, wt1, bl1, br1, xl1, xr1, N_NODES, ei, hist);

    // D3-D5: CSR scan + scatter
    scan1_kernel<<<196, 256, 0, stream>>>(hist, rowptr, bsum);
    scan3_kernel<<<196, 256, 0, stream>>>(rowptr, bsum, off);
    scatter_kernel<<<eb, 256, 0, stream>>>(ei, off, src_csr);

    // D6-D8: node1, lin2, node2
    const int nb = (N_NODES * 64 + 255) / 256;   // 12500 blocks
    node1_kernel<<<nb, 256, 0, stream>>>(xl1, xr1, rowptr, hist, src_csr, att1, bias1, hbuf);
    lin2_fused_kernel<<<(N_NODES + 63) / 64, 256, 0, stream>>>(hbuf, wt2, bl2, br2, xl2, xr2, N_NODES);
    node2_kernel<<<nb, 256, 0, stream>>>(xl2, xr2, rowptr, hist, src_csr, att2, bias2, d_out,
                                         (const unsigned*)x);
}